// Round 2
// baseline (1668.595 us; speedup 1.0000x reference)
//
#include <hip/hip_runtime.h>
#include <cstdint>
#include <cstddef>

// Problem constants (fixed by the reference setup)
#define BS    2048
#define DIN   1024
#define DOUT  1024
#define SSEG  10
#define NPAR  30720          // dout * S * 3
#define NCOL  31744          // NPAR + DOUT (norm columns appended)
#define NLG   10240          // S * DOUT logit columns (channel 0)
#define TAU   3e-4f          // near-boundary detection radius (75 sigma of logit-GEMM error)
#define WL_CAP 1048576u      // worklist capacity (entries)

typedef _Float16 half_t;
typedef __attribute__((ext_vector_type(8))) _Float16 half8;
typedef __attribute__((ext_vector_type(4))) _Float16 half4;
typedef __attribute__((ext_vector_type(4))) float   floatx4;

__device__ __forceinline__ void gload16(const void* g, void* l) {
  // global -> LDS direct copy, 16B/lane; LDS base must be wave-uniform,
  // HW scatters lane L to base + L*16.
  __builtin_amdgcn_global_load_lds(
      (const __attribute__((address_space(1))) void*)g,
      (__attribute__((address_space(3))) void*)l, 16, 0, 0);
}

// ---------------------------------------------------------------------------
__global__ void k_zero(unsigned* c) { if (threadIdx.x == 0) *c = 0; }

// ---------------------------------------------------------------------------
// x (fp32) -> xh = fp16(x), xl = fp16(x - xh)   (fp16x2 split; xh doubles as
// the A operand of the plain fp16 GEMM)
// ---------------------------------------------------------------------------
__global__ __launch_bounds__(256) void k_split_x(const float* __restrict__ x,
                                                 half_t* __restrict__ xh,
                                                 half_t* __restrict__ xl) {
  int i = blockIdx.x * 256 + threadIdx.x;      // float4 groups
  floatx4 v = ((const floatx4*)x)[i];
  half4 h, l;
  #pragma unroll
  for (int c = 0; c < 4; c++) { h[c] = (half_t)v[c]; l[c] = (half_t)(v[c] - (float)h[c]); }
  ((half4*)xh)[i] = h;
  ((half4*)xl)[i] = l;
}

// ---------------------------------------------------------------------------
// Transpose+convert W (fp32, DIN x ncols) -> WT (fp16, ncols x DIN)
// ---------------------------------------------------------------------------
__global__ __launch_bounds__(256) void k_transpose(const float* __restrict__ src,
                                                   half_t* __restrict__ dst,
                                                   int ncols, int col_off) {
  __shared__ float tile[32][33];
  int tx = threadIdx.x & 31;
  int ty = threadIdx.x >> 5;
  int col0 = blockIdx.x * 32;
  int k0   = blockIdx.y * 32;
  #pragma unroll
  for (int r = ty; r < 32; r += 8)
    tile[r][tx] = src[(size_t)(k0 + r) * ncols + col0 + tx];
  __syncthreads();
  #pragma unroll
  for (int r = ty; r < 32; r += 8)
    dst[(size_t)(col0 + r + col_off) * DIN + k0 + tx] = (half_t)tile[tx][r];
}

// ---------------------------------------------------------------------------
// Logit columns of param_W: scale x32 (exact), fp16x2 split, transposed.
// Packed logit col index lcol = s*1024 + d  <->  orig col s*3072 + 3d.
// ---------------------------------------------------------------------------
__global__ __launch_bounds__(256) void k_transpose_logit(const float* __restrict__ src,
                                                         half_t* __restrict__ dh,
                                                         half_t* __restrict__ dl) {
  __shared__ float tile[32][33];
  int tx = threadIdx.x & 31;
  int ty = threadIdx.x >> 5;
  int c0 = blockIdx.x * 32;                    // 1024 % 32 == 0: s constant per block
  int k0 = blockIdx.y * 32;
  int lcol = c0 + tx;
  int scol = (lcol >> 10) * 3072 + (lcol & 1023) * 3;
  #pragma unroll
  for (int r = ty; r < 32; r += 8)
    tile[r][tx] = src[(size_t)(k0 + r) * NPAR + scol];
  __syncthreads();
  #pragma unroll
  for (int r = ty; r < 32; r += 8) {
    float v = tile[tx][r] * 32.0f;             // exact pow2 scale keeps lo part normal
    half_t h = (half_t)v;
    half_t l = (half_t)(v - (float)h);
    dh[(size_t)(c0 + r) * DIN + k0 + tx] = h;
    dl[(size_t)(c0 + r) * DIN + k0 + tx] = l;
  }
}

// ---------------------------------------------------------------------------
// Main fp16 GEMM: P(BS x NCOL, fp32) = xh * WT^T + bias (smooth channels)
// ---------------------------------------------------------------------------
__global__ __launch_bounds__(256) void k_gemm(const half_t* __restrict__ A,
                                              const half_t* __restrict__ B,
                                              float* __restrict__ C,
                                              const float* __restrict__ pb,
                                              const float* __restrict__ nb) {
  __shared__ __attribute__((aligned(16))) half_t As[128 * 32];
  __shared__ __attribute__((aligned(16))) half_t Bs[128 * 32];
  const int K = DIN;
  int m0 = blockIdx.y * 128, n0 = blockIdx.x * 128;
  int tid = threadIdx.x, w = tid >> 6, L = tid & 63;
  int wm = (w >> 1) * 64, wn = (w & 1) * 64;
  int l15 = L & 15, quad = L >> 4;

  const half_t* ga = A + (size_t)(m0 + w * 16 + (L >> 2)) * K + (L & 3) * 8;
  const half_t* gb = B + (size_t)(n0 + w * 16 + (L >> 2)) * K + (L & 3) * 8;
  char* lA = (char*)As + w * 1024;
  char* lB = (char*)Bs + w * 1024;

  floatx4 acc[4][4] = {};

  for (int k0 = 0; k0 < K; k0 += 32) {
    __syncthreads();
    gload16(ga + k0,          lA);
    gload16(ga + 64 * K + k0, lA + 4096);
    gload16(gb + k0,          lB);
    gload16(gb + 64 * K + k0, lB + 4096);
    __syncthreads();

    half8 af[4], bf[4];
    #pragma unroll
    for (int mi = 0; mi < 4; mi++)
      af[mi] = *(const half8*)((const char*)As + (wm + mi * 16 + l15) * 64 + quad * 16);
    #pragma unroll
    for (int ni = 0; ni < 4; ni++)
      bf[ni] = *(const half8*)((const char*)Bs + (wn + ni * 16 + l15) * 64 + quad * 16);
    #pragma unroll
    for (int mi = 0; mi < 4; mi++)
      #pragma unroll
      for (int ni = 0; ni < 4; ni++)
        acc[mi][ni] = __builtin_amdgcn_mfma_f32_16x16x32_f16(af[mi], bf[ni], acc[mi][ni], 0, 0, 0);
  }

  #pragma unroll
  for (int ni = 0; ni < 4; ni++) {
    int col = n0 + wn + ni * 16 + l15;
    float bias = (col < NPAR) ? pb[col] : nb[col - NPAR];
    #pragma unroll
    for (int mi = 0; mi < 4; mi++) {
      int row = m0 + wm + mi * 16 + quad * 4;
      floatx4 v = acc[mi][ni];
      #pragma unroll
      for (int r = 0; r < 4; r++)
        C[(size_t)(row + r) * NCOL + col] = v[r] + bias;
    }
  }
}

// ---------------------------------------------------------------------------
// Logit GEMM, fp16x2: Lg(BS x NLG) = (xh+xl)(wh+wl)^T/32 + bias, dropping xl*wl.
// 3 MFMAs per fragment pair; fp32 accumulation. delta_logit ~ 2e-6.
// ---------------------------------------------------------------------------
__global__ __launch_bounds__(256) void k_gemm_logit(const half_t* __restrict__ Ah,
                                                    const half_t* __restrict__ Al,
                                                    const half_t* __restrict__ Bh,
                                                    const half_t* __restrict__ Bl,
                                                    float* __restrict__ Lg,
                                                    const float* __restrict__ pb) {
  __shared__ __attribute__((aligned(16))) half_t sAh[128 * 32];
  __shared__ __attribute__((aligned(16))) half_t sAl[128 * 32];
  __shared__ __attribute__((aligned(16))) half_t sBh[128 * 32];
  __shared__ __attribute__((aligned(16))) half_t sBl[128 * 32];
  const int K = DIN;
  int m0 = blockIdx.y * 128, n0 = blockIdx.x * 128;
  int tid = threadIdx.x, w = tid >> 6, L = tid & 63;
  int wm = (w >> 1) * 64, wn = (w & 1) * 64;
  int l15 = L & 15, quad = L >> 4;

  size_t aoff = (size_t)(m0 + w * 16 + (L >> 2)) * K + (L & 3) * 8;
  size_t boff = (size_t)(n0 + w * 16 + (L >> 2)) * K + (L & 3) * 8;
  char* lah = (char*)sAh + w * 1024;
  char* lal = (char*)sAl + w * 1024;
  char* lbh = (char*)sBh + w * 1024;
  char* lbl = (char*)sBl + w * 1024;

  floatx4 acc[4][4] = {};

  for (int k0 = 0; k0 < K; k0 += 32) {
    __syncthreads();
    gload16(Ah + aoff + k0,          lah);
    gload16(Ah + aoff + 64 * K + k0, lah + 4096);
    gload16(Al + aoff + k0,          lal);
    gload16(Al + aoff + 64 * K + k0, lal + 4096);
    gload16(Bh + boff + k0,          lbh);
    gload16(Bh + boff + 64 * K + k0, lbh + 4096);
    gload16(Bl + boff + k0,          lbl);
    gload16(Bl + boff + 64 * K + k0, lbl + 4096);
    __syncthreads();

    #pragma unroll
    for (int mi = 0; mi < 4; mi++) {
      half8 afh = *(const half8*)((const char*)sAh + (wm + mi * 16 + l15) * 64 + quad * 16);
      half8 afl = *(const half8*)((const char*)sAl + (wm + mi * 16 + l15) * 64 + quad * 16);
      #pragma unroll
      for (int ni = 0; ni < 4; ni++) {
        half8 bfh = *(const half8*)((const char*)sBh + (wn + ni * 16 + l15) * 64 + quad * 16);
        half8 bfl = *(const half8*)((const char*)sBl + (wn + ni * 16 + l15) * 64 + quad * 16);
        floatx4 a = acc[mi][ni];
        a = __builtin_amdgcn_mfma_f32_16x16x32_f16(afh, bfh, a, 0, 0, 0);
        a = __builtin_amdgcn_mfma_f32_16x16x32_f16(afl, bfh, a, 0, 0, 0);
        a = __builtin_amdgcn_mfma_f32_16x16x32_f16(afh, bfl, a, 0, 0, 0);
        acc[mi][ni] = a;
      }
    }
  }

  #pragma unroll
  for (int ni = 0; ni < 4; ni++) {
    int col = n0 + wn + ni * 16 + l15;                       // packed s*1024+d
    float bias = pb[(col >> 10) * 3072 + (col & 1023) * 3];
    #pragma unroll
    for (int mi = 0; mi < 4; mi++) {
      int row = m0 + wm + mi * 16 + quad * 4;
      floatx4 v = acc[mi][ni];
      #pragma unroll
      for (int r = 0; r < 4; r++)
        Lg[(size_t)(row + r) * NLG + col] = v[r] * 0.03125f + bias;
    }
  }
}

// ---------------------------------------------------------------------------
// fp32 formula (bias-included params). mind = min_j |t - kp[j]| for flagging.
// ---------------------------------------------------------------------------
__device__ __forceinline__ float spiking_eval(const float* p, float tt, float* mind) {
  float mx = -1e30f;
  #pragma unroll
  for (int s = 0; s < SSEG; s++) mx = fmaxf(mx, p[3 * s]);
  float ew[10], wsum = 0.0f;
  #pragma unroll
  for (int s = 0; s < SSEG; s++) { ew[s] = __expf(p[3 * s] - mx); wsum += ew[s]; }
  float inv = 1.0f / wsum;

  float kp[11];
  kp[0] = -1.0f;
  float cum = 0.0f, md = 1e30f;
  #pragma unroll
  for (int s = 0; s < SSEG; s++) {
    cum += ew[s] * inv;
    kp[s + 1] = cum * 2.0f - 1.0f;
    md = fminf(md, fabsf(tt - kp[s + 1]));
  }
  *mind = md;

  float vf[10], resid[10];
  float lm = 0.0f, rm = 0.0f, integ = 0.0f;
  #pragma unroll
  for (int s = 0; s < SSEG; s++) {
    float p1 = p[3 * s + 1], p2 = p[3 * s + 2];
    float e2 = __expf(2.0f * fabsf(p1));
    float th = copysignf(1.0f - 2.0f / (e2 + 1.0f), p1);
    resid[s] = th * tt + p2;
    float st = kp[s], en = kp[s + 1];
    bool v = ((tt >= st) && (tt < en)) || ((tt == 1.0f) && (en == 1.0f));
    float vv = v ? 1.0f : 0.0f;
    vf[s] = vv;
    lm += (tt - st) * vv;
    rm += (en - tt) * vv;
    integ += 0.5f * th * (en * en - st * st) + p2 * (ew[s] * inv);
  }
  float resLV = 0.0f, resV = 0.0f, resRV = 0.0f;
  #pragma unroll
  for (int s = 0; s < SSEG; s++) {
    float lv = (s == 0) ? vf[0] : vf[s - 1];
    float rv = (s == 9) ? vf[9] : vf[s + 1];
    resLV += resid[s] * lv;
    resV  += resid[s] * vf[s];
    resRV += resid[s] * rv;
  }
  float lw = 1.0f / (1.0f + __expf(50.0f * lm));
  float rw = 1.0f / (1.0f + __expf(50.0f * rm));
  float swt = 1.0f - lw - rw;
  return lw * resLV + swt * resV + rw * resRV - 0.5f * integ + p[30];
}

// ---------------------------------------------------------------------------
// Pointwise: logits from Lg (fp16x2-accurate), ch1/2+norm from P. Flags
// near-boundary elements into the worklist.
// ---------------------------------------------------------------------------
__global__ __launch_bounds__(256) void k_pointwise(const float* __restrict__ P,
                                                   const float* __restrict__ Lg,
                                                   const float* __restrict__ t,
                                                   float* __restrict__ out,
                                                   unsigned* __restrict__ cnt,
                                                   unsigned* __restrict__ wl,
                                                   unsigned cap) {
  __shared__ __attribute__((aligned(16))) float sp[SSEG * 768];
  int b = blockIdx.x, dg = blockIdx.y, tid = threadIdx.x;
  const float* Pb = P + (size_t)b * NCOL;
  for (int i = tid; i < SSEG * 192; i += 256) {
    int s = i / 192, e = i - s * 192;
    ((floatx4*)sp)[s * 192 + e] = ((const floatx4*)(Pb + s * 3072 + dg * 768))[e];
  }
  float tt = t[b];
  float nt = Pb[NPAR + dg * 256 + tid];
  const float* Lb = Lg + (size_t)b * NLG + dg * 256 + tid;
  __syncthreads();

  float p[31];
  #pragma unroll
  for (int s = 0; s < SSEG; s++) {
    p[3 * s]     = Lb[s * 1024];                 // accurate logit (bias incl.)
    p[3 * s + 1] = sp[s * 768 + 3 * tid + 1];
    p[3 * s + 2] = sp[s * 768 + 3 * tid + 2];
  }
  p[30] = nt;
  float mind;
  float r = spiking_eval(p, tt, &mind);
  int d = dg * 256 + tid;
  out[(size_t)b * DOUT + d] = r;
  if (wl != nullptr && mind < TAU) {
    unsigned idx = atomicAdd(cnt, 1u);
    if (idx < cap) wl[idx] = ((unsigned)b << 10) | (unsigned)d;
  }
}

// ---------------------------------------------------------------------------
// Fallback: fused naive fp32 (zero big scratch) + flagging.
// ---------------------------------------------------------------------------
__global__ __launch_bounds__(256) void k_naive(const float* __restrict__ x,
                                               const float* __restrict__ t,
                                               const float* __restrict__ pW,
                                               const float* __restrict__ pb,
                                               const float* __restrict__ nW,
                                               const float* __restrict__ nb,
                                               float* __restrict__ out,
                                               unsigned* __restrict__ cnt,
                                               unsigned* __restrict__ wl,
                                               unsigned cap) {
  __shared__ float xs[DIN];
  int b = blockIdx.x, dg = blockIdx.y, tid = threadIdx.x;
  for (int i = tid; i < DIN; i += 256) xs[i] = x[(size_t)b * DIN + i];
  __syncthreads();
  int d = dg * 256 + tid;
  float acc[31];
  #pragma unroll
  for (int i = 0; i < 31; i++) acc[i] = 0.0f;
  for (int k = 0; k < DIN; k++) {
    float xv = xs[k];
    const float* wr = pW + (size_t)k * NPAR + 3 * d;
    #pragma unroll
    for (int s = 0; s < SSEG; s++) {
      acc[3 * s]     += xv * wr[s * 3072];
      acc[3 * s + 1] += xv * wr[s * 3072 + 1];
      acc[3 * s + 2] += xv * wr[s * 3072 + 2];
    }
    acc[30] += xv * nW[(size_t)k * DOUT + d];
  }
  #pragma unroll
  for (int s = 0; s < SSEG; s++) {
    acc[3 * s]     += pb[s * 3072 + 3 * d];
    acc[3 * s + 1] += pb[s * 3072 + 3 * d + 1];
    acc[3 * s + 2] += pb[s * 3072 + 3 * d + 2];
  }
  acc[30] += nb[d];
  float mind;
  float r = spiking_eval(acc, t[b], &mind);
  out[(size_t)b * DOUT + d] = r;
  if (wl != nullptr && mind < TAU) {
    unsigned idx = atomicAdd(cnt, 1u);
    if (idx < cap) wl[idx] = ((unsigned)b << 10) | (unsigned)d;
  }
}

// ---------------------------------------------------------------------------
// f64 redo: one wave per flagged (b,d). Exact logits/softmax/keypoints and
// full formula in double; smooth channels from P (fp32) when available.
// ---------------------------------------------------------------------------
__global__ __launch_bounds__(256) void k_redo(const float* __restrict__ x,
                                              const float* __restrict__ t,
                                              const float* __restrict__ pW,
                                              const float* __restrict__ pb,
                                              const float* __restrict__ nW,
                                              const float* __restrict__ nb,
                                              const float* __restrict__ P,
                                              int haveP,
                                              const unsigned* __restrict__ cnt,
                                              const unsigned* __restrict__ wl,
                                              unsigned cap,
                                              float* __restrict__ out) {
  unsigned n = *cnt;
  if (n > cap) n = cap;
  int lane = threadIdx.x & 63;
  unsigned wave = (blockIdx.x * 256 + threadIdx.x) >> 6;
  unsigned nwaves = (gridDim.x * 256) >> 6;

  for (unsigned e = wave; e < n; e += nwaves) {
    unsigned code = wl[e];
    int b = (int)(code >> 10), d = (int)(code & 1023);

    double lg[10], sl[10], ic[10], nt = 0.0;
    #pragma unroll
    for (int s = 0; s < SSEG; s++) { lg[s] = 0.0; sl[s] = 0.0; ic[s] = 0.0; }

    for (int k = lane; k < DIN; k += 64) {
      double xv = (double)x[(size_t)b * DIN + k];
      const float* wr = pW + (size_t)k * NPAR + 3 * d;
      #pragma unroll
      for (int s = 0; s < SSEG; s++) lg[s] += xv * (double)wr[s * 3072];
      if (!haveP) {
        #pragma unroll
        for (int s = 0; s < SSEG; s++) {
          sl[s] += xv * (double)wr[s * 3072 + 1];
          ic[s] += xv * (double)wr[s * 3072 + 2];
        }
        nt += xv * (double)nW[(size_t)k * DOUT + d];
      }
    }
    #pragma unroll
    for (int off = 32; off > 0; off >>= 1) {
      #pragma unroll
      for (int s = 0; s < SSEG; s++) lg[s] += __shfl_down(lg[s], off);
      if (!haveP) {
        #pragma unroll
        for (int s = 0; s < SSEG; s++) {
          sl[s] += __shfl_down(sl[s], off);
          ic[s] += __shfl_down(ic[s], off);
        }
        nt += __shfl_down(nt, off);
      }
    }

    if (lane == 0) {
      double slope[10], icpt[10], ntv;
      if (haveP) {
        const float* Pr = P + (size_t)b * NCOL;
        #pragma unroll
        for (int s = 0; s < SSEG; s++) {
          slope[s] = tanh((double)Pr[s * 3072 + 3 * d + 1]);
          icpt[s]  = (double)Pr[s * 3072 + 3 * d + 2];
        }
        ntv = (double)Pr[NPAR + d];
      } else {
        #pragma unroll
        for (int s = 0; s < SSEG; s++) {
          slope[s] = tanh(sl[s] + (double)pb[s * 3072 + 3 * d + 1]);
          icpt[s]  = ic[s] + (double)pb[s * 3072 + 3 * d + 2];
        }
        ntv = nt + (double)nb[d];
      }
      #pragma unroll
      for (int s = 0; s < SSEG; s++) lg[s] += (double)pb[s * 3072 + 3 * d];

      double mx = -1e300;
      #pragma unroll
      for (int s = 0; s < SSEG; s++) mx = fmax(mx, lg[s]);
      double ew[10], ws = 0.0;
      #pragma unroll
      for (int s = 0; s < SSEG; s++) { ew[s] = exp(lg[s] - mx); ws += ew[s]; }

      double kp[11];
      kp[0] = -1.0;
      double cum = 0.0;
      #pragma unroll
      for (int s = 0; s < SSEG; s++) { cum += ew[s] / ws; kp[s + 1] = cum * 2.0 - 1.0; }

      double tt = (double)t[b];
      double vf[10], resid[10], lm = 0.0, rm = 0.0, integ = 0.0;
      #pragma unroll
      for (int s = 0; s < SSEG; s++) {
        double st = kp[s], en = kp[s + 1];
        bool v = ((tt >= st) && (tt < en)) || ((tt == 1.0) && (en == 1.0));
        double vv = v ? 1.0 : 0.0;
        vf[s] = vv;
        resid[s] = slope[s] * tt + icpt[s];
        lm += (tt - st) * vv;
        rm += (en - tt) * vv;
        integ += 0.5 * slope[s] * (en * en - st * st) + icpt[s] * (ew[s] / ws);
      }
      double rLV = 0.0, rV = 0.0, rRV = 0.0;
      #pragma unroll
      for (int s = 0; s < SSEG; s++) {
        double lv = (s == 0) ? vf[0] : vf[s - 1];
        double rv = (s == 9) ? vf[9] : vf[s + 1];
        rLV += resid[s] * lv;
        rV  += resid[s] * vf[s];
        rRV += resid[s] * rv;
      }
      double lw = 1.0 / (1.0 + exp(50.0 * lm));
      double rw = 1.0 / (1.0 + exp(50.0 * rm));
      double res = lw * rLV + (1.0 - lw - rw) * rV + rw * rRV - 0.5 * integ + ntv;
      out[(size_t)b * DOUT + d] = (float)res;
    }
  }
}

// ---------------------------------------------------------------------------
extern "C" void kernel_launch(void* const* d_in, const int* in_sizes, int n_in,
                              void* d_out, int out_size, void* d_ws, size_t ws_size,
                              hipStream_t stream) {
  const float* x  = (const float*)d_in[0];
  const float* t  = (const float*)d_in[1];
  const float* pW = (const float*)d_in[2];
  const float* pb = (const float*)d_in[3];
  const float* nW = (const float*)d_in[4];
  const float* nb = (const float*)d_in[5];
  float* out = (float*)d_out;

  // workspace layout (counter+worklist first so the fallback works with tiny ws)
  const size_t o_cnt = 0;
  const size_t o_wl  = 64;
  const size_t o_xh  = o_wl  + (size_t)WL_CAP * 4;        //  4 MiB
  const size_t o_xl  = o_xh  + (size_t)BS * DIN * 2;
  const size_t o_wt  = o_xl  + (size_t)BS * DIN * 2;
  const size_t o_wh  = o_wt  + (size_t)NCOL * DIN * 2;
  const size_t o_wlo = o_wh  + (size_t)NLG * DIN * 2;
  const size_t o_p   = o_wlo + (size_t)NLG * DIN * 2;
  const size_t o_lg  = o_p   + (size_t)BS * NCOL * 4;
  const size_t need  = o_lg  + (size_t)BS * NLG * 4;      // ~443 MiB total

  bool have_wl = ws_size >= 1024 * 1024;
  unsigned* cnt = (unsigned*)((char*)d_ws + o_cnt);
  unsigned* wl  = (unsigned*)((char*)d_ws + o_wl);
  unsigned cap  = 0;
  if (have_wl) {
    size_t avail = (ws_size >= need) ? (size_t)WL_CAP
                                     : (ws_size - o_wl) / 4;
    cap = (unsigned)(avail < WL_CAP ? avail : WL_CAP);
    k_zero<<<1, 64, 0, stream>>>(cnt);
  }

  if (ws_size >= need) {
    half_t* xh  = (half_t*)((char*)d_ws + o_xh);
    half_t* xl  = (half_t*)((char*)d_ws + o_xl);
    half_t* wt  = (half_t*)((char*)d_ws + o_wt);
    half_t* wh  = (half_t*)((char*)d_ws + o_wh);
    half_t* wlo = (half_t*)((char*)d_ws + o_wlo);
    float*  P   = (float*)((char*)d_ws + o_p);
    float*  Lg  = (float*)((char*)d_ws + o_lg);

    k_split_x<<<(BS * DIN) / 1024, 256, 0, stream>>>(x, xh, xl);
    k_transpose<<<dim3(NPAR / 32, DIN / 32), 256, 0, stream>>>(pW, wt, NPAR, 0);
    k_transpose<<<dim3(DOUT / 32, DIN / 32), 256, 0, stream>>>(nW, wt, DOUT, NPAR);
    k_transpose_logit<<<dim3(NLG / 32, DIN / 32), 256, 0, stream>>>(pW, wh, wlo);
    k_gemm<<<dim3(NCOL / 128, BS / 128), 256, 0, stream>>>(xh, wt, P, pb, nb);
    k_gemm_logit<<<dim3(NLG / 128, BS / 128), 256, 0, stream>>>(xh, xl, wh, wlo, Lg, pb);
    k_pointwise<<<dim3(BS, DOUT / 256), 256, 0, stream>>>(P, Lg, t, out, cnt,
                                                          have_wl ? wl : nullptr, cap);
    if (have_wl)
      k_redo<<<256, 256, 0, stream>>>(x, t, pW, pb, nW, nb, P, 1, cnt, wl, cap, out);
  } else {
    k_naive<<<dim3(BS, DOUT / 256), 256, 0, stream>>>(x, t, pW, pb, nW, nb, out, cnt,
                                                      have_wl ? wl : nullptr, cap);
    if (have_wl)
      k_redo<<<256, 256, 0, stream>>>(x, t, pW, pb, nW, nb, nullptr, 0, cnt, wl, cap, out);
  }
}

// Round 3
// 642.367 us; speedup vs baseline: 2.5976x; 2.5976x over previous
//
#include <hip/hip_runtime.h>
#include <cstdint>
#include <cstddef>

// Problem constants (fixed by the reference setup)
#define BS    2048
#define DIN   1024
#define DOUT  1024
#define SSEG  10
#define NPAR  30720          // dout * S * 3
#define NPK   20480          // packed smooth cols: S*DOUT*2 (ch1,ch2)
#define NCOL2 21504          // NPK + DOUT (norm appended)
#define NLG   10240          // S * DOUT logit columns (channel 0)
#define TAU   5e-5f          // near-boundary radius (~10x worst fp32-pipeline kp error)
#define WL_CAP 1048576u      // worklist capacity (entries)

typedef _Float16 half_t;
typedef __attribute__((ext_vector_type(8))) _Float16 half8;
typedef __attribute__((ext_vector_type(4))) _Float16 half4;
typedef __attribute__((ext_vector_type(4))) float   floatx4;

__device__ __forceinline__ void gload16(const void* g, void* l) {
  __builtin_amdgcn_global_load_lds(
      (const __attribute__((address_space(1))) void*)g,
      (__attribute__((address_space(3))) void*)l, 16, 0, 0);
}

// ---------------------------------------------------------------------------
__global__ void k_zero(unsigned* c) { if (threadIdx.x == 0) *c = 0; }

// ---------------------------------------------------------------------------
// x (fp32) -> xh = fp16(x), xl = fp16(x - xh)
// ---------------------------------------------------------------------------
__global__ __launch_bounds__(256) void k_split_x(const float* __restrict__ x,
                                                 half_t* __restrict__ xh,
                                                 half_t* __restrict__ xl) {
  int i = blockIdx.x * 256 + threadIdx.x;      // float4 groups
  floatx4 v = ((const floatx4*)x)[i];
  half4 h, l;
  #pragma unroll
  for (int c = 0; c < 4; c++) { h[c] = (half_t)v[c]; l[c] = (half_t)(v[c] - (float)h[c]); }
  ((half4*)xh)[i] = h;
  ((half4*)xl)[i] = l;
}

// ---------------------------------------------------------------------------
// Packed smooth transpose: ch1/ch2 of param_W -> WT rows [0, NPK)
// packed col j = s*2048 + d*2 + c  <->  orig col s*3072 + 3d + 1 + c
// ---------------------------------------------------------------------------
__global__ __launch_bounds__(256) void k_transpose_pk(const float* __restrict__ src,
                                                      half_t* __restrict__ dst) {
  __shared__ float tile[32][33];
  int tx = threadIdx.x & 31;
  int ty = threadIdx.x >> 5;
  int c0 = blockIdx.x * 32;
  int k0 = blockIdx.y * 32;
  int j = c0 + tx;
  int s = j >> 11, rem = j & 2047;
  int scol = s * 3072 + 3 * (rem >> 1) + 1 + (rem & 1);
  #pragma unroll
  for (int r = ty; r < 32; r += 8)
    tile[r][tx] = src[(size_t)(k0 + r) * NPAR + scol];
  __syncthreads();
  #pragma unroll
  for (int r = ty; r < 32; r += 8)
    dst[(size_t)(c0 + r) * DIN + k0 + tx] = (half_t)tile[tx][r];
}

// ---------------------------------------------------------------------------
// Norm transpose: norm_W -> WT rows [NPK, NCOL2)
// ---------------------------------------------------------------------------
__global__ __launch_bounds__(256) void k_transpose(const float* __restrict__ src,
                                                   half_t* __restrict__ dst,
                                                   int ncols, int col_off) {
  __shared__ float tile[32][33];
  int tx = threadIdx.x & 31;
  int ty = threadIdx.x >> 5;
  int col0 = blockIdx.x * 32;
  int k0   = blockIdx.y * 32;
  #pragma unroll
  for (int r = ty; r < 32; r += 8)
    tile[r][tx] = src[(size_t)(k0 + r) * ncols + col0 + tx];
  __syncthreads();
  #pragma unroll
  for (int r = ty; r < 32; r += 8)
    dst[(size_t)(col0 + r + col_off) * DIN + k0 + tx] = (half_t)tile[tx][r];
}

// ---------------------------------------------------------------------------
// Logit cols: x32 scale (exact), fp16x2 split (wh/wlo) + exact fp32 copy (wlt)
// packed logit col lcol = s*1024 + d  <->  orig col s*3072 + 3d
// ---------------------------------------------------------------------------
__global__ __launch_bounds__(256) void k_transpose_logit(const float* __restrict__ src,
                                                         half_t* __restrict__ dh,
                                                         half_t* __restrict__ dl,
                                                         float* __restrict__ wlt) {
  __shared__ float tile[32][33];
  int tx = threadIdx.x & 31;
  int ty = threadIdx.x >> 5;
  int c0 = blockIdx.x * 32;
  int k0 = blockIdx.y * 32;
  int lcol = c0 + tx;
  int scol = (lcol >> 10) * 3072 + (lcol & 1023) * 3;
  #pragma unroll
  for (int r = ty; r < 32; r += 8)
    tile[r][tx] = src[(size_t)(k0 + r) * NPAR + scol];
  __syncthreads();
  #pragma unroll
  for (int r = ty; r < 32; r += 8) {
    float raw = tile[tx][r];
    float v = raw * 32.0f;
    half_t h = (half_t)v;
    half_t l = (half_t)(v - (float)h);
    dh [(size_t)(c0 + r) * DIN + k0 + tx] = h;
    dl [(size_t)(c0 + r) * DIN + k0 + tx] = l;
    wlt[(size_t)(c0 + r) * DIN + k0 + tx] = raw;     // exact fp32, K-contiguous
  }
}

// ---------------------------------------------------------------------------
// Main fp16 GEMM (smooth channels only): P2(BS x NCOL2) = xh * WT^T + bias
// ---------------------------------------------------------------------------
__global__ __launch_bounds__(256) void k_gemm(const half_t* __restrict__ A,
                                              const half_t* __restrict__ B,
                                              float* __restrict__ C,
                                              const float* __restrict__ pb,
                                              const float* __restrict__ nb) {
  __shared__ __attribute__((aligned(16))) half_t As[128 * 32];
  __shared__ __attribute__((aligned(16))) half_t Bs[128 * 32];
  const int K = DIN;
  int m0 = blockIdx.y * 128, n0 = blockIdx.x * 128;
  int tid = threadIdx.x, w = tid >> 6, L = tid & 63;
  int wm = (w >> 1) * 64, wn = (w & 1) * 64;
  int l15 = L & 15, quad = L >> 4;

  const half_t* ga = A + (size_t)(m0 + w * 16 + (L >> 2)) * K + (L & 3) * 8;
  const half_t* gb = B + (size_t)(n0 + w * 16 + (L >> 2)) * K + (L & 3) * 8;
  char* lA = (char*)As + w * 1024;
  char* lB = (char*)Bs + w * 1024;

  floatx4 acc[4][4] = {};

  for (int k0 = 0; k0 < K; k0 += 32) {
    __syncthreads();
    gload16(ga + k0,          lA);
    gload16(ga + 64 * K + k0, lA + 4096);
    gload16(gb + k0,          lB);
    gload16(gb + 64 * K + k0, lB + 4096);
    __syncthreads();

    half8 af[4], bf[4];
    #pragma unroll
    for (int mi = 0; mi < 4; mi++)
      af[mi] = *(const half8*)((const char*)As + (wm + mi * 16 + l15) * 64 + quad * 16);
    #pragma unroll
    for (int ni = 0; ni < 4; ni++)
      bf[ni] = *(const half8*)((const char*)Bs + (wn + ni * 16 + l15) * 64 + quad * 16);
    #pragma unroll
    for (int mi = 0; mi < 4; mi++)
      #pragma unroll
      for (int ni = 0; ni < 4; ni++)
        acc[mi][ni] = __builtin_amdgcn_mfma_f32_16x16x32_f16(af[mi], bf[ni], acc[mi][ni], 0, 0, 0);
  }

  #pragma unroll
  for (int ni = 0; ni < 4; ni++) {
    int col = n0 + wn + ni * 16 + l15;
    float bias;
    if (col < NPK) {
      int s = col >> 11, rem = col & 2047;
      bias = pb[s * 3072 + 3 * (rem >> 1) + 1 + (rem & 1)];
    } else {
      bias = nb[col - NPK];
    }
    #pragma unroll
    for (int mi = 0; mi < 4; mi++) {
      int row = m0 + wm + mi * 16 + quad * 4;
      floatx4 v = acc[mi][ni];
      #pragma unroll
      for (int r = 0; r < 4; r++)
        C[(size_t)(row + r) * NCOL2 + col] = v[r] + bias;
    }
  }
}

// ---------------------------------------------------------------------------
// Logit GEMM, fp16x2: Lg = (xh+xl)(wh+wl)^T/32 + bias (drop xl*wl term)
// ---------------------------------------------------------------------------
__global__ __launch_bounds__(256) void k_gemm_logit(const half_t* __restrict__ Ah,
                                                    const half_t* __restrict__ Al,
                                                    const half_t* __restrict__ Bh,
                                                    const half_t* __restrict__ Bl,
                                                    float* __restrict__ Lg,
                                                    const float* __restrict__ pb) {
  __shared__ __attribute__((aligned(16))) half_t sAh[128 * 32];
  __shared__ __attribute__((aligned(16))) half_t sAl[128 * 32];
  __shared__ __attribute__((aligned(16))) half_t sBh[128 * 32];
  __shared__ __attribute__((aligned(16))) half_t sBl[128 * 32];
  const int K = DIN;
  int m0 = blockIdx.y * 128, n0 = blockIdx.x * 128;
  int tid = threadIdx.x, w = tid >> 6, L = tid & 63;
  int wm = (w >> 1) * 64, wn = (w & 1) * 64;
  int l15 = L & 15, quad = L >> 4;

  size_t aoff = (size_t)(m0 + w * 16 + (L >> 2)) * K + (L & 3) * 8;
  size_t boff = (size_t)(n0 + w * 16 + (L >> 2)) * K + (L & 3) * 8;
  char* lah = (char*)sAh + w * 1024;
  char* lal = (char*)sAl + w * 1024;
  char* lbh = (char*)sBh + w * 1024;
  char* lbl = (char*)sBl + w * 1024;

  floatx4 acc[4][4] = {};

  for (int k0 = 0; k0 < K; k0 += 32) {
    __syncthreads();
    gload16(Ah + aoff + k0,          lah);
    gload16(Ah + aoff + 64 * K + k0, lah + 4096);
    gload16(Al + aoff + k0,          lal);
    gload16(Al + aoff + 64 * K + k0, lal + 4096);
    gload16(Bh + boff + k0,          lbh);
    gload16(Bh + boff + 64 * K + k0, lbh + 4096);
    gload16(Bl + boff + k0,          lbl);
    gload16(Bl + boff + 64 * K + k0, lbl + 4096);
    __syncthreads();

    #pragma unroll
    for (int mi = 0; mi < 4; mi++) {
      half8 afh = *(const half8*)((const char*)sAh + (wm + mi * 16 + l15) * 64 + quad * 16);
      half8 afl = *(const half8*)((const char*)sAl + (wm + mi * 16 + l15) * 64 + quad * 16);
      #pragma unroll
      for (int ni = 0; ni < 4; ni++) {
        half8 bfh = *(const half8*)((const char*)sBh + (wn + ni * 16 + l15) * 64 + quad * 16);
        half8 bfl = *(const half8*)((const char*)sBl + (wn + ni * 16 + l15) * 64 + quad * 16);
        floatx4 a = acc[mi][ni];
        a = __builtin_amdgcn_mfma_f32_16x16x32_f16(afh, bfh, a, 0, 0, 0);
        a = __builtin_amdgcn_mfma_f32_16x16x32_f16(afl, bfh, a, 0, 0, 0);
        a = __builtin_amdgcn_mfma_f32_16x16x32_f16(afh, bfl, a, 0, 0, 0);
        acc[mi][ni] = a;
      }
    }
  }

  #pragma unroll
  for (int ni = 0; ni < 4; ni++) {
    int col = n0 + wn + ni * 16 + l15;                       // packed s*1024+d
    float bias = pb[(col >> 10) * 3072 + (col & 1023) * 3];
    #pragma unroll
    for (int mi = 0; mi < 4; mi++) {
      int row = m0 + wm + mi * 16 + quad * 4;
      floatx4 v = acc[mi][ni];
      #pragma unroll
      for (int r = 0; r < 4; r++)
        Lg[(size_t)(row + r) * NLG + col] = v[r] * 0.03125f + bias;
    }
  }
}

// ---------------------------------------------------------------------------
// fp32 formula; mind = min_j |t - kp[j]| for near-boundary flagging
// ---------------------------------------------------------------------------
__device__ __forceinline__ float spiking_eval(const float* p, float tt, float* mind) {
  float mx = -1e30f;
  #pragma unroll
  for (int s = 0; s < SSEG; s++) mx = fmaxf(mx, p[3 * s]);
  float ew[10], wsum = 0.0f;
  #pragma unroll
  for (int s = 0; s < SSEG; s++) { ew[s] = __expf(p[3 * s] - mx); wsum += ew[s]; }
  float inv = 1.0f / wsum;

  float kp[11];
  kp[0] = -1.0f;
  float cum = 0.0f, md = 1e30f;
  #pragma unroll
  for (int s = 0; s < SSEG; s++) {
    cum += ew[s] * inv;
    kp[s + 1] = cum * 2.0f - 1.0f;
    md = fminf(md, fabsf(tt - kp[s + 1]));
  }
  *mind = md;

  float vf[10], resid[10];
  float lm = 0.0f, rm = 0.0f, integ = 0.0f;
  #pragma unroll
  for (int s = 0; s < SSEG; s++) {
    float p1 = p[3 * s + 1], p2 = p[3 * s + 2];
    float e2 = __expf(2.0f * fabsf(p1));
    float th = copysignf(1.0f - 2.0f / (e2 + 1.0f), p1);
    resid[s] = th * tt + p2;
    float st = kp[s], en = kp[s + 1];
    bool v = ((tt >= st) && (tt < en)) || ((tt == 1.0f) && (en == 1.0f));
    float vv = v ? 1.0f : 0.0f;
    vf[s] = vv;
    lm += (tt - st) * vv;
    rm += (en - tt) * vv;
    integ += 0.5f * th * (en * en - st * st) + p2 * (ew[s] * inv);
  }
  float resLV = 0.0f, resV = 0.0f, resRV = 0.0f;
  #pragma unroll
  for (int s = 0; s < SSEG; s++) {
    float lv = (s == 0) ? vf[0] : vf[s - 1];
    float rv = (s == 9) ? vf[9] : vf[s + 1];
    resLV += resid[s] * lv;
    resV  += resid[s] * vf[s];
    resRV += resid[s] * rv;
  }
  float lw = 1.0f / (1.0f + __expf(50.0f * lm));
  float rw = 1.0f / (1.0f + __expf(50.0f * rm));
  float swt = 1.0f - lw - rw;
  return lw * resLV + swt * resV + rw * resRV - 0.5f * integ + p[30];
}

// ---------------------------------------------------------------------------
// Pointwise: logits from Lg, ch1/2+norm from packed P2. Flags near-boundary.
// ---------------------------------------------------------------------------
__global__ __launch_bounds__(256) void k_pointwise(const float* __restrict__ P,
                                                   const float* __restrict__ Lg,
                                                   const float* __restrict__ t,
                                                   float* __restrict__ out,
                                                   unsigned* __restrict__ cnt,
                                                   unsigned* __restrict__ wl,
                                                   unsigned cap) {
  __shared__ __attribute__((aligned(16))) float sp[SSEG * 512];
  int b = blockIdx.x, dg = blockIdx.y, tid = threadIdx.x;
  const float* Pb = P + (size_t)b * NCOL2;
  for (int i = tid; i < SSEG * 128; i += 256) {
    int s = i >> 7, e = i & 127;
    ((floatx4*)sp)[s * 128 + e] = ((const floatx4*)(Pb + s * 2048 + dg * 512))[e];
  }
  float tt = t[b];
  float nt = Pb[NPK + dg * 256 + tid];
  const float* Lb = Lg + (size_t)b * NLG + dg * 256 + tid;
  __syncthreads();

  float p[31];
  #pragma unroll
  for (int s = 0; s < SSEG; s++) {
    p[3 * s]     = Lb[s * 1024];                 // accurate logit (bias incl.)
    p[3 * s + 1] = sp[s * 512 + 2 * tid];        // 2-way bank alias: free
    p[3 * s + 2] = sp[s * 512 + 2 * tid + 1];
  }
  p[30] = nt;
  float mind;
  float r = spiking_eval(p, tt, &mind);
  int d = dg * 256 + tid;
  out[(size_t)b * DOUT + d] = r;
  if (wl != nullptr && mind < TAU) {
    unsigned idx = atomicAdd(cnt, 1u);
    if (idx < cap) wl[idx] = ((unsigned)b << 10) | (unsigned)d;
  }
}

// ---------------------------------------------------------------------------
// Fallback: fused naive fp32 + flagging (tiny-workspace insurance)
// ---------------------------------------------------------------------------
__global__ __launch_bounds__(256) void k_naive(const float* __restrict__ x,
                                               const float* __restrict__ t,
                                               const float* __restrict__ pW,
                                               const float* __restrict__ pb,
                                               const float* __restrict__ nW,
                                               const float* __restrict__ nb,
                                               float* __restrict__ out,
                                               unsigned* __restrict__ cnt,
                                               unsigned* __restrict__ wl,
                                               unsigned cap) {
  __shared__ float xs[DIN];
  int b = blockIdx.x, dg = blockIdx.y, tid = threadIdx.x;
  for (int i = tid; i < DIN; i += 256) xs[i] = x[(size_t)b * DIN + i];
  __syncthreads();
  int d = dg * 256 + tid;
  float acc[31];
  #pragma unroll
  for (int i = 0; i < 31; i++) acc[i] = 0.0f;
  for (int k = 0; k < DIN; k++) {
    float xv = xs[k];
    const float* wr = pW + (size_t)k * NPAR + 3 * d;
    #pragma unroll
    for (int s = 0; s < SSEG; s++) {
      acc[3 * s]     += xv * wr[s * 3072];
      acc[3 * s + 1] += xv * wr[s * 3072 + 1];
      acc[3 * s + 2] += xv * wr[s * 3072 + 2];
    }
    acc[30] += xv * nW[(size_t)k * DOUT + d];
  }
  #pragma unroll
  for (int s = 0; s < SSEG; s++) {
    acc[3 * s]     += pb[s * 3072 + 3 * d];
    acc[3 * s + 1] += pb[s * 3072 + 3 * d + 1];
    acc[3 * s + 2] += pb[s * 3072 + 3 * d + 2];
  }
  acc[30] += nb[d];
  float mind;
  float r = spiking_eval(acc, t[b], &mind);
  out[(size_t)b * DOUT + d] = r;
  if (wl != nullptr && mind < TAU) {
    unsigned idx = atomicAdd(cnt, 1u);
    if (idx < cap) wl[idx] = ((unsigned)b << 10) | (unsigned)d;
  }
}

// ---------------------------------------------------------------------------
// f64 redo: one wave per flagged (b,d). haveP: coalesced fp32 logit weights
// from WLt + smooth channels from packed P2. !haveP: pW gather (fallback).
// ---------------------------------------------------------------------------
__global__ __launch_bounds__(256) void k_redo(const float* __restrict__ x,
                                              const float* __restrict__ t,
                                              const float* __restrict__ pW,
                                              const float* __restrict__ pb,
                                              const float* __restrict__ nW,
                                              const float* __restrict__ nb,
                                              const float* __restrict__ P,
                                              const float* __restrict__ WLt,
                                              int haveP,
                                              const unsigned* __restrict__ cnt,
                                              const unsigned* __restrict__ wl,
                                              unsigned cap,
                                              float* __restrict__ out) {
  unsigned n = *cnt;
  if (n > cap) n = cap;
  int lane = threadIdx.x & 63;
  unsigned wave = (blockIdx.x * 256 + threadIdx.x) >> 6;
  unsigned nwaves = (gridDim.x * 256) >> 6;

  for (unsigned e = wave; e < n; e += nwaves) {
    unsigned code = wl[e];
    int b = (int)(code >> 10), d = (int)(code & 1023);

    double lg[10], sl[10], ic[10], nt = 0.0;
    #pragma unroll
    for (int s = 0; s < SSEG; s++) { lg[s] = 0.0; sl[s] = 0.0; ic[s] = 0.0; }

    if (haveP) {
      // coalesced: lane L reads k = L, L+64, ... from K-contiguous WLt rows
      for (int k = lane; k < DIN; k += 64) {
        double xv = (double)x[(size_t)b * DIN + k];
        #pragma unroll
        for (int s = 0; s < SSEG; s++)
          lg[s] += xv * (double)WLt[(size_t)(s * 1024 + d) * DIN + k];
      }
    } else {
      for (int k = lane; k < DIN; k += 64) {
        double xv = (double)x[(size_t)b * DIN + k];
        const float* wr = pW + (size_t)k * NPAR + 3 * d;
        #pragma unroll
        for (int s = 0; s < SSEG; s++) {
          lg[s] += xv * (double)wr[s * 3072];
          sl[s] += xv * (double)wr[s * 3072 + 1];
          ic[s] += xv * (double)wr[s * 3072 + 2];
        }
        nt += xv * (double)nW[(size_t)k * DOUT + d];
      }
    }
    #pragma unroll
    for (int off = 32; off > 0; off >>= 1) {
      #pragma unroll
      for (int s = 0; s < SSEG; s++) lg[s] += __shfl_down(lg[s], off);
      if (!haveP) {
        #pragma unroll
        for (int s = 0; s < SSEG; s++) {
          sl[s] += __shfl_down(sl[s], off);
          ic[s] += __shfl_down(ic[s], off);
        }
        nt += __shfl_down(nt, off);
      }
    }

    if (lane == 0) {
      double slope[10], icpt[10], ntv;
      if (haveP) {
        const float* Pr = P + (size_t)b * NCOL2;
        #pragma unroll
        for (int s = 0; s < SSEG; s++) {
          slope[s] = tanh((double)Pr[s * 2048 + 2 * d]);
          icpt[s]  = (double)Pr[s * 2048 + 2 * d + 1];
        }
        ntv = (double)Pr[NPK + d];
      } else {
        #pragma unroll
        for (int s = 0; s < SSEG; s++) {
          slope[s] = tanh(sl[s] + (double)pb[s * 3072 + 3 * d + 1]);
          icpt[s]  = ic[s] + (double)pb[s * 3072 + 3 * d + 2];
        }
        ntv = nt + (double)nb[d];
      }
      #pragma unroll
      for (int s = 0; s < SSEG; s++) lg[s] += (double)pb[s * 3072 + 3 * d];

      double mx = -1e300;
      #pragma unroll
      for (int s = 0; s < SSEG; s++) mx = fmax(mx, lg[s]);
      double ew[10], ws = 0.0;
      #pragma unroll
      for (int s = 0; s < SSEG; s++) { ew[s] = exp(lg[s] - mx); ws += ew[s]; }

      double kp[11];
      kp[0] = -1.0;
      double cum = 0.0;
      #pragma unroll
      for (int s = 0; s < SSEG; s++) { cum += ew[s] / ws; kp[s + 1] = cum * 2.0 - 1.0; }

      double tt = (double)t[b];
      double vf[10], resid[10], lm = 0.0, rm = 0.0, integ = 0.0;
      #pragma unroll
      for (int s = 0; s < SSEG; s++) {
        double st = kp[s], en = kp[s + 1];
        bool v = ((tt >= st) && (tt < en)) || ((tt == 1.0) && (en == 1.0));
        double vv = v ? 1.0 : 0.0;
        vf[s] = vv;
        resid[s] = slope[s] * tt + icpt[s];
        lm += (tt - st) * vv;
        rm += (en - tt) * vv;
        integ += 0.5 * slope[s] * (en * en - st * st) + icpt[s] * (ew[s] / ws);
      }
      double rLV = 0.0, rV = 0.0, rRV = 0.0;
      #pragma unroll
      for (int s = 0; s < SSEG; s++) {
        double lv = (s == 0) ? vf[0] : vf[s - 1];
        double rv = (s == 9) ? vf[9] : vf[s + 1];
        rLV += resid[s] * lv;
        rV  += resid[s] * vf[s];
        rRV += resid[s] * rv;
      }
      double lw = 1.0 / (1.0 + exp(50.0 * lm));
      double rw = 1.0 / (1.0 + exp(50.0 * rm));
      double res = lw * rLV + (1.0 - lw - rw) * rV + rw * rRV - 0.5 * integ + ntv;
      out[(size_t)b * DOUT + d] = (float)res;
    }
  }
}

// ---------------------------------------------------------------------------
extern "C" void kernel_launch(void* const* d_in, const int* in_sizes, int n_in,
                              void* d_out, int out_size, void* d_ws, size_t ws_size,
                              hipStream_t stream) {
  const float* x  = (const float*)d_in[0];
  const float* t  = (const float*)d_in[1];
  const float* pW = (const float*)d_in[2];
  const float* pb = (const float*)d_in[3];
  const float* nW = (const float*)d_in[4];
  const float* nb = (const float*)d_in[5];
  float* out = (float*)d_out;

  // workspace layout (counter+worklist first so the fallback works with tiny ws)
  const size_t o_cnt = 0;
  const size_t o_wl  = 64;
  const size_t o_xh  = o_wl  + (size_t)WL_CAP * 4;         //  4 MiB
  const size_t o_xl  = o_xh  + (size_t)BS * DIN * 2;       //  4 MiB
  const size_t o_wt  = o_xl  + (size_t)BS * DIN * 2;       // 44 MiB (NCOL2 fp16)
  const size_t o_wh  = o_wt  + (size_t)NCOL2 * DIN * 2;    // 20 MiB
  const size_t o_wlo = o_wh  + (size_t)NLG * DIN * 2;      // 20 MiB
  const size_t o_wlt = o_wlo + (size_t)NLG * DIN * 2;      // 40 MiB (fp32 logit W^T)
  const size_t o_p   = o_wlt + (size_t)NLG * DIN * 4;      // 176 MiB (packed P2)
  const size_t o_lg  = o_p   + (size_t)BS * NCOL2 * 4;     // 84 MiB
  const size_t need  = o_lg  + (size_t)BS * NLG * 4;       // ~396 MiB total

  bool have_wl = ws_size >= 1024 * 1024;
  unsigned* cnt = (unsigned*)((char*)d_ws + o_cnt);
  unsigned* wl  = (unsigned*)((char*)d_ws + o_wl);
  unsigned cap  = 0;
  if (have_wl) {
    size_t avail = (ws_size >= need) ? (size_t)WL_CAP
                                     : (ws_size - o_wl) / 4;
    cap = (unsigned)(avail < WL_CAP ? avail : WL_CAP);
    k_zero<<<1, 64, 0, stream>>>(cnt);
  }

  if (ws_size >= need) {
    half_t* xh  = (half_t*)((char*)d_ws + o_xh);
    half_t* xl  = (half_t*)((char*)d_ws + o_xl);
    half_t* wt  = (half_t*)((char*)d_ws + o_wt);
    half_t* wh  = (half_t*)((char*)d_ws + o_wh);
    half_t* wlo = (half_t*)((char*)d_ws + o_wlo);
    float*  wlt = (float*)((char*)d_ws + o_wlt);
    float*  P   = (float*)((char*)d_ws + o_p);
    float*  Lg  = (float*)((char*)d_ws + o_lg);

    k_split_x<<<(BS * DIN) / 1024, 256, 0, stream>>>(x, xh, xl);
    k_transpose_pk<<<dim3(NPK / 32, DIN / 32), 256, 0, stream>>>(pW, wt);
    k_transpose<<<dim3(DOUT / 32, DIN / 32), 256, 0, stream>>>(nW, wt, DOUT, NPK);
    k_transpose_logit<<<dim3(NLG / 32, DIN / 32), 256, 0, stream>>>(pW, wh, wlo, wlt);
    k_gemm<<<dim3(NCOL2 / 128, BS / 128), 256, 0, stream>>>(xh, wt, P, pb, nb);
    k_gemm_logit<<<dim3(NLG / 128, BS / 128), 256, 0, stream>>>(xh, xl, wh, wlo, Lg, pb);
    k_pointwise<<<dim3(BS, DOUT / 256), 256, 0, stream>>>(P, Lg, t, out, cnt,
                                                          have_wl ? wl : nullptr, cap);
    if (have_wl)
      k_redo<<<256, 256, 0, stream>>>(x, t, pW, pb, nW, nb, P, wlt, 1, cnt, wl, cap, out);
  } else {
    k_naive<<<dim3(BS, DOUT / 256), 256, 0, stream>>>(x, t, pW, pb, nW, nb, out, cnt,
                                                      have_wl ? wl : nullptr, cap);
    if (have_wl)
      k_redo<<<256, 256, 0, stream>>>(x, t, pW, pb, nW, nb, nullptr, nullptr, 0,
                                      cnt, wl, cap, out);
  }
}

// Round 4
// 629.887 us; speedup vs baseline: 2.6490x; 1.0198x over previous
//
#include <hip/hip_runtime.h>
#include <cstdint>
#include <cstddef>

// Problem constants (fixed by the reference setup)
#define BS    2048
#define DIN   1024
#define DOUT  1024
#define SSEG  10
#define NPAR  30720          // dout * S * 3
#define NPK   20480          // packed smooth cols: S*DOUT*2 (ch1,ch2)
#define NCOL2 21504          // NPK + DOUT (norm appended)
#define NLG   10240          // S * DOUT logit columns (channel 0)
#define NT_LG 80             // logit n-tiles (first in merged GEMM grid)
#define NT_SM 168            // smooth n-tiles
#define TAU   5e-5f          // near-boundary radius (~10x worst fp32-pipeline kp error)
#define WL_CAP 1048576u      // worklist capacity (entries)

typedef _Float16 half_t;
typedef __attribute__((ext_vector_type(8))) _Float16 half8;
typedef __attribute__((ext_vector_type(4))) _Float16 half4;
typedef __attribute__((ext_vector_type(2))) _Float16 half2v;
typedef __attribute__((ext_vector_type(4))) float   floatx4;

__device__ __forceinline__ void gload16(const void* g, void* l) {
  __builtin_amdgcn_global_load_lds(
      (const __attribute__((address_space(1))) void*)g,
      (__attribute__((address_space(3))) void*)l, 16, 0, 0);
}

// ---------------------------------------------------------------------------
__global__ void k_zero(unsigned* c) { if (threadIdx.x == 0) *c = 0; }

// ---------------------------------------------------------------------------
// x (fp32) -> xh = fp16(x), xl = fp16(x - xh). Also zeroes the worklist cnt.
// ---------------------------------------------------------------------------
__global__ __launch_bounds__(256) void k_split_x(const float* __restrict__ x,
                                                 half_t* __restrict__ xh,
                                                 half_t* __restrict__ xl,
                                                 unsigned* __restrict__ cnt) {
  if (blockIdx.x == 0 && threadIdx.x == 0) *cnt = 0;
  int i = blockIdx.x * 256 + threadIdx.x;      // float4 groups
  floatx4 v = ((const floatx4*)x)[i];
  half4 h, l;
  #pragma unroll
  for (int c = 0; c < 4; c++) { h[c] = (half_t)v[c]; l[c] = (half_t)(v[c] - (float)h[c]); }
  ((half4*)xh)[i] = h;
  ((half4*)xl)[i] = l;
}

// ---------------------------------------------------------------------------
// Merged W transpose: one coalesced pass over param_W emitting
//  - wsm  [NPK][DIN] fp16 : packed ch1/ch2 (col s*2048+2d+c)
//  - wh/wlo [NLG][DIN] fp16x2 of 32*w (logit cols, col s*1024+d)
//  - wlt  [NLG][DIN] fp32 exact logit weights (for coalesced f64 redo)
// Block: 32 k-rows x 384 src cols (= 128 d x 3ch, s fixed since 384|3072).
// ---------------------------------------------------------------------------
__global__ __launch_bounds__(256) void k_transw(const float* __restrict__ src,
                                                half_t* __restrict__ wsm,
                                                half_t* __restrict__ wh,
                                                half_t* __restrict__ wlo,
                                                float* __restrict__ wlt) {
  __shared__ float tile[32][384];
  int bx = blockIdx.x;                 // 0..79
  int k0 = blockIdx.y * 32;
  int tid = threadIdx.x;
  int s  = bx >> 3;                    // logit segment (3072-col group)
  int d0 = (bx & 7) * 128;
  const float* sb = src + (size_t)k0 * NPAR + bx * 384;
  for (int i = tid; i < 32 * 96; i += 256) {     // 12 fully-coalesced float4/thread
    int r = i / 96, q = i - r * 96;
    ((floatx4*)&tile[r][0])[q] = ((const floatx4*)(sb + (size_t)r * NPAR))[q];
  }
  __syncthreads();
  int j   = tid & 127;                 // d offset
  int ks  = (tid >> 7) * 16;           // k half-segment
  // ch0 -> wh/wlo/wlt (LDS col reads: bank (3j)%32, 2-way alias = free)
  {
    size_t row = (size_t)(s * 1024 + d0 + j) * DIN + k0 + ks;
    #pragma unroll
    for (int m = 0; m < 16; m++) {
      float raw = tile[ks + m][3 * j];
      float v = raw * 32.0f;           // exact pow2 scale keeps lo part normal
      half_t h = (half_t)v;
      wlt[row + m] = raw;
      wh [row + m] = h;
      wlo[row + m] = (half_t)(v - (float)h);
    }
  }
  // ch1/ch2 -> wsm
  #pragma unroll
  for (int c = 0; c < 2; c++) {
    size_t row = (size_t)(s * 2048 + 2 * (d0 + j) + c) * DIN + k0 + ks;
    #pragma unroll
    for (int m = 0; m < 16; m++)
      wsm[row + m] = (half_t)tile[ks + m][3 * j + 1 + c];
  }
}

// ---------------------------------------------------------------------------
// Norm transpose: norm_W -> wsm rows [NPK, NCOL2)
// ---------------------------------------------------------------------------
__global__ __launch_bounds__(256) void k_transpose(const float* __restrict__ src,
                                                   half_t* __restrict__ dst,
                                                   int ncols, int col_off) {
  __shared__ float tile[32][33];
  int tx = threadIdx.x & 31;
  int ty = threadIdx.x >> 5;
  int col0 = blockIdx.x * 32;
  int k0   = blockIdx.y * 32;
  #pragma unroll
  for (int r = ty; r < 32; r += 8)
    tile[r][tx] = src[(size_t)(k0 + r) * ncols + col0 + tx];
  __syncthreads();
  #pragma unroll
  for (int r = ty; r < 32; r += 8)
    dst[(size_t)(col0 + r + col_off) * DIN + k0 + tx] = (half_t)tile[tx][r];
}

// ---------------------------------------------------------------------------
// Merged GEMM. n-tiles [0,80): logit fp16x2 3-pass -> Lg fp32.
//              n-tiles [80,248): smooth 1-pass -> P fp16 (+bias).
// m97 structure: 128x128 tile, BK=32, 4 waves 2x2, global_load_lds w=16.
// ---------------------------------------------------------------------------
__global__ __launch_bounds__(256) void k_gemm_all(const half_t* __restrict__ Ah,
                                                  const half_t* __restrict__ Al,
                                                  const half_t* __restrict__ Wsm,
                                                  const half_t* __restrict__ Bh,
                                                  const half_t* __restrict__ Bl,
                                                  half_t* __restrict__ P,
                                                  float* __restrict__ Lg,
                                                  const float* __restrict__ pb,
                                                  const float* __restrict__ nb) {
  __shared__ __attribute__((aligned(16))) half_t s0[128 * 32];
  __shared__ __attribute__((aligned(16))) half_t s1[128 * 32];
  __shared__ __attribute__((aligned(16))) half_t s2[128 * 32];
  __shared__ __attribute__((aligned(16))) half_t s3[128 * 32];
  const int K = DIN;
  int bx = blockIdx.x;
  int m0 = blockIdx.y * 128;
  int tid = threadIdx.x, w = tid >> 6, L = tid & 63;
  int wm = (w >> 1) * 64, wn = (w & 1) * 64;
  int l15 = L & 15, quad = L >> 4;

  size_t arow = (size_t)(m0 + w * 16 + (L >> 2)) * K + (L & 3) * 8;
  char* l0 = (char*)s0 + w * 1024;
  char* l1 = (char*)s1 + w * 1024;
  char* l2 = (char*)s2 + w * 1024;
  char* l3 = (char*)s3 + w * 1024;

  floatx4 acc[4][4] = {};

  if (bx < NT_LG) {
    // ---- logit region: fp16x2, 3 MFMA passes ----
    int n0 = bx * 128;
    size_t brow = (size_t)(n0 + w * 16 + (L >> 2)) * K + (L & 3) * 8;

    for (int k0 = 0; k0 < K; k0 += 32) {
      __syncthreads();
      gload16(Ah + arow + k0,          l0);
      gload16(Ah + arow + 64 * K + k0, l0 + 4096);
      gload16(Al + arow + k0,          l1);
      gload16(Al + arow + 64 * K + k0, l1 + 4096);
      gload16(Bh + brow + k0,          l2);
      gload16(Bh + brow + 64 * K + k0, l2 + 4096);
      gload16(Bl + brow + k0,          l3);
      gload16(Bl + brow + 64 * K + k0, l3 + 4096);
      __syncthreads();

      #pragma unroll
      for (int mi = 0; mi < 4; mi++) {
        half8 afh = *(const half8*)((const char*)s0 + (wm + mi * 16 + l15) * 64 + quad * 16);
        half8 afl = *(const half8*)((const char*)s1 + (wm + mi * 16 + l15) * 64 + quad * 16);
        #pragma unroll
        for (int ni = 0; ni < 4; ni++) {
          half8 bfh = *(const half8*)((const char*)s2 + (wn + ni * 16 + l15) * 64 + quad * 16);
          half8 bfl = *(const half8*)((const char*)s3 + (wn + ni * 16 + l15) * 64 + quad * 16);
          floatx4 a = acc[mi][ni];
          a = __builtin_amdgcn_mfma_f32_16x16x32_f16(afh, bfh, a, 0, 0, 0);
          a = __builtin_amdgcn_mfma_f32_16x16x32_f16(afl, bfh, a, 0, 0, 0);
          a = __builtin_amdgcn_mfma_f32_16x16x32_f16(afh, bfl, a, 0, 0, 0);
          acc[mi][ni] = a;
        }
      }
    }

    #pragma unroll
    for (int ni = 0; ni < 4; ni++) {
      int col = n0 + wn + ni * 16 + l15;                     // packed s*1024+d
      float bias = pb[(col >> 10) * 3072 + (col & 1023) * 3];
      #pragma unroll
      for (int mi = 0; mi < 4; mi++) {
        int row = m0 + wm + mi * 16 + quad * 4;
        floatx4 v = acc[mi][ni];
        #pragma unroll
        for (int r = 0; r < 4; r++)
          Lg[(size_t)(row + r) * NLG + col] = v[r] * 0.03125f + bias;
      }
    }
  } else {
    // ---- smooth region: plain fp16, 1 pass ----
    int n0 = (bx - NT_LG) * 128;
    size_t brow = (size_t)(n0 + w * 16 + (L >> 2)) * K + (L & 3) * 8;

    for (int k0 = 0; k0 < K; k0 += 32) {
      __syncthreads();
      gload16(Ah + arow + k0,           l0);
      gload16(Ah + arow + 64 * K + k0,  l0 + 4096);
      gload16(Wsm + brow + k0,          l2);
      gload16(Wsm + brow + 64 * K + k0, l2 + 4096);
      __syncthreads();

      half8 af[4], bf[4];
      #pragma unroll
      for (int mi = 0; mi < 4; mi++)
        af[mi] = *(const half8*)((const char*)s0 + (wm + mi * 16 + l15) * 64 + quad * 16);
      #pragma unroll
      for (int ni = 0; ni < 4; ni++)
        bf[ni] = *(const half8*)((const char*)s2 + (wn + ni * 16 + l15) * 64 + quad * 16);
      #pragma unroll
      for (int mi = 0; mi < 4; mi++)
        #pragma unroll
        for (int ni = 0; ni < 4; ni++)
          acc[mi][ni] = __builtin_amdgcn_mfma_f32_16x16x32_f16(af[mi], bf[ni], acc[mi][ni], 0, 0, 0);
    }

    #pragma unroll
    for (int ni = 0; ni < 4; ni++) {
      int col = n0 + wn + ni * 16 + l15;
      float bias;
      if (col < NPK) {
        int s = col >> 11, rem = col & 2047;
        bias = pb[s * 3072 + 3 * (rem >> 1) + 1 + (rem & 1)];
      } else {
        bias = nb[col - NPK];
      }
      #pragma unroll
      for (int mi = 0; mi < 4; mi++) {
        int row = m0 + wm + mi * 16 + quad * 4;
        floatx4 v = acc[mi][ni];
        #pragma unroll
        for (int r = 0; r < 4; r++)
          P[(size_t)(row + r) * NCOL2 + col] = (half_t)(v[r] + bias);
      }
    }
  }
}

// ---------------------------------------------------------------------------
// fp32 formula; mind = min_j |t - kp[j]| for near-boundary flagging
// ---------------------------------------------------------------------------
__device__ __forceinline__ float spiking_eval(const float* p, float tt, float* mind) {
  float mx = -1e30f;
  #pragma unroll
  for (int s = 0; s < SSEG; s++) mx = fmaxf(mx, p[3 * s]);
  float ew[10], wsum = 0.0f;
  #pragma unroll
  for (int s = 0; s < SSEG; s++) { ew[s] = __expf(p[3 * s] - mx); wsum += ew[s]; }
  float inv = 1.0f / wsum;

  float kp[11];
  kp[0] = -1.0f;
  float cum = 0.0f, md = 1e30f;
  #pragma unroll
  for (int s = 0; s < SSEG; s++) {
    cum += ew[s] * inv;
    kp[s + 1] = cum * 2.0f - 1.0f;
    md = fminf(md, fabsf(tt - kp[s + 1]));
  }
  *mind = md;

  float vf[10], resid[10];
  float lm = 0.0f, rm = 0.0f, integ = 0.0f;
  #pragma unroll
  for (int s = 0; s < SSEG; s++) {
    float p1 = p[3 * s + 1], p2 = p[3 * s + 2];
    float e2 = __expf(2.0f * fabsf(p1));
    float th = copysignf(1.0f - 2.0f / (e2 + 1.0f), p1);
    resid[s] = th * tt + p2;
    float st = kp[s], en = kp[s + 1];
    bool v = ((tt >= st) && (tt < en)) || ((tt == 1.0f) && (en == 1.0f));
    float vv = v ? 1.0f : 0.0f;
    vf[s] = vv;
    lm += (tt - st) * vv;
    rm += (en - tt) * vv;
    integ += 0.5f * th * (en * en - st * st) + p2 * (ew[s] * inv);
  }
  float resLV = 0.0f, resV = 0.0f, resRV = 0.0f;
  #pragma unroll
  for (int s = 0; s < SSEG; s++) {
    float lv = (s == 0) ? vf[0] : vf[s - 1];
    float rv = (s == 9) ? vf[9] : vf[s + 1];
    resLV += resid[s] * lv;
    resV  += resid[s] * vf[s];
    resRV += resid[s] * rv;
  }
  float lw = 1.0f / (1.0f + __expf(50.0f * lm));
  float rw = 1.0f / (1.0f + __expf(50.0f * rm));
  float swt = 1.0f - lw - rw;
  return lw * resLV + swt * resV + rw * resRV - 0.5f * integ + p[30];
}

// ---------------------------------------------------------------------------
// Pointwise: logits fp32 from Lg, ch1/2+norm fp16 from P. Flags near-boundary.
// ---------------------------------------------------------------------------
__global__ __launch_bounds__(256) void k_pointwise(const half_t* __restrict__ P,
                                                   const float* __restrict__ Lg,
                                                   const float* __restrict__ t,
                                                   float* __restrict__ out,
                                                   unsigned* __restrict__ cnt,
                                                   unsigned* __restrict__ wl,
                                                   unsigned cap) {
  __shared__ __attribute__((aligned(16))) half_t sp[SSEG * 512];
  int b = blockIdx.x, dg = blockIdx.y, tid = threadIdx.x;
  const half_t* Pb = P + (size_t)b * NCOL2;
  for (int i = tid; i < SSEG * 64; i += 256) {     // 640 x 16B
    int s = i >> 6, e = i & 63;
    ((uint4*)sp)[(s << 6) + e] = ((const uint4*)(Pb + s * 2048 + dg * 512))[e];
  }
  float tt = t[b];
  float nt = (float)Pb[NPK + dg * 256 + tid];
  const float* Lb = Lg + (size_t)b * NLG + dg * 256 + tid;
  __syncthreads();

  float p[31];
  #pragma unroll
  for (int s = 0; s < SSEG; s++) {
    p[3 * s] = Lb[s * 1024];                       // accurate logit (bias incl.)
    half2v hv = ((const half2v*)sp)[s * 256 + tid];  // 4B/lane, conflict-free
    p[3 * s + 1] = (float)hv.x;
    p[3 * s + 2] = (float)hv.y;
  }
  p[30] = nt;
  float mind;
  float r = spiking_eval(p, tt, &mind);
  int d = dg * 256 + tid;
  out[(size_t)b * DOUT + d] = r;
  if (wl != nullptr && mind < TAU) {
    unsigned idx = atomicAdd(cnt, 1u);
    if (idx < cap) wl[idx] = ((unsigned)b << 10) | (unsigned)d;
  }
}

// ---------------------------------------------------------------------------
// Fallback: fused naive fp32 + flagging (tiny-workspace insurance)
// ---------------------------------------------------------------------------
__global__ __launch_bounds__(256) void k_naive(const float* __restrict__ x,
                                               const float* __restrict__ t,
                                               const float* __restrict__ pW,
                                               const float* __restrict__ pb,
                                               const float* __restrict__ nW,
                                               const float* __restrict__ nb,
                                               float* __restrict__ out,
                                               unsigned* __restrict__ cnt,
                                               unsigned* __restrict__ wl,
                                               unsigned cap) {
  __shared__ float xs[DIN];
  int b = blockIdx.x, dg = blockIdx.y, tid = threadIdx.x;
  for (int i = tid; i < DIN; i += 256) xs[i] = x[(size_t)b * DIN + i];
  __syncthreads();
  int d = dg * 256 + tid;
  float acc[31];
  #pragma unroll
  for (int i = 0; i < 31; i++) acc[i] = 0.0f;
  for (int k = 0; k < DIN; k++) {
    float xv = xs[k];
    const float* wr = pW + (size_t)k * NPAR + 3 * d;
    #pragma unroll
    for (int s = 0; s < SSEG; s++) {
      acc[3 * s]     += xv * wr[s * 3072];
      acc[3 * s + 1] += xv * wr[s * 3072 + 1];
      acc[3 * s + 2] += xv * wr[s * 3072 + 2];
    }
    acc[30] += xv * nW[(size_t)k * DOUT + d];
  }
  #pragma unroll
  for (int s = 0; s < SSEG; s++) {
    acc[3 * s]     += pb[s * 3072 + 3 * d];
    acc[3 * s + 1] += pb[s * 3072 + 3 * d + 1];
    acc[3 * s + 2] += pb[s * 3072 + 3 * d + 2];
  }
  acc[30] += nb[d];
  float mind;
  float r = spiking_eval(acc, t[b], &mind);
  out[(size_t)b * DOUT + d] = r;
  if (wl != nullptr && mind < TAU) {
    unsigned idx = atomicAdd(cnt, 1u);
    if (idx < cap) wl[idx] = ((unsigned)b << 10) | (unsigned)d;
  }
}

// ---------------------------------------------------------------------------
// f64 redo: one wave per flagged (b,d). haveP: coalesced WLt logit weights +
// fp16 smooth channels from P. !haveP: pW gather (fallback path).
// ---------------------------------------------------------------------------
__global__ __launch_bounds__(256) void k_redo(const float* __restrict__ x,
                                              const float* __restrict__ t,
                                              const float* __restrict__ pW,
                                              const float* __restrict__ pb,
                                              const float* __restrict__ nW,
                                              const float* __restrict__ nb,
                                              const half_t* __restrict__ P,
                                              const float* __restrict__ WLt,
                                              int haveP,
                                              const unsigned* __restrict__ cnt,
                                              const unsigned* __restrict__ wl,
                                              unsigned cap,
                                              float* __restrict__ out) {
  unsigned n = *cnt;
  if (n > cap) n = cap;
  int lane = threadIdx.x & 63;
  unsigned wave = (blockIdx.x * 256 + threadIdx.x) >> 6;
  unsigned nwaves = (gridDim.x * 256) >> 6;

  for (unsigned e = wave; e < n; e += nwaves) {
    unsigned code = wl[e];
    int b = (int)(code >> 10), d = (int)(code & 1023);

    double lg[10], sl[10], ic[10], nt = 0.0;
    #pragma unroll
    for (int s = 0; s < SSEG; s++) { lg[s] = 0.0; sl[s] = 0.0; ic[s] = 0.0; }

    if (haveP) {
      for (int k = lane; k < DIN; k += 64) {     // coalesced WLt rows
        double xv = (double)x[(size_t)b * DIN + k];
        #pragma unroll
        for (int s = 0; s < SSEG; s++)
          lg[s] += xv * (double)WLt[(size_t)(s * 1024 + d) * DIN + k];
      }
    } else {
      for (int k = lane; k < DIN; k += 64) {
        double xv = (double)x[(size_t)b * DIN + k];
        const float* wr = pW + (size_t)k * NPAR + 3 * d;
        #pragma unroll
        for (int s = 0; s < SSEG; s++) {
          lg[s] += xv * (double)wr[s * 3072];
          sl[s] += xv * (double)wr[s * 3072 + 1];
          ic[s] += xv * (double)wr[s * 3072 + 2];
        }
        nt += xv * (double)nW[(size_t)k * DOUT + d];
      }
    }
    #pragma unroll
    for (int off = 32; off > 0; off >>= 1) {
      #pragma unroll
      for (int s = 0; s < SSEG; s++) lg[s] += __shfl_down(lg[s], off);
      if (!haveP) {
        #pragma unroll
        for (int s = 0; s < SSEG; s++) {
          sl[s] += __shfl_down(sl[s], off);
          ic[s] += __shfl_down(ic[s], off);
        }
        nt += __shfl_down(nt, off);
      }
    }

    if (lane == 0) {
      double slope[10], icpt[10], ntv;
      if (haveP) {
        const half_t* Pr = P + (size_t)b * NCOL2;
        #pragma unroll
        for (int s = 0; s < SSEG; s++) {
          slope[s] = tanh((double)(float)Pr[s * 2048 + 2 * d]);
          icpt[s]  = (double)(float)Pr[s * 2048 + 2 * d + 1];
        }
        ntv = (double)(float)Pr[NPK + d];
      } else {
        #pragma unroll
        for (int s = 0; s < SSEG; s++) {
          slope[s] = tanh(sl[s] + (double)pb[s * 3072 + 3 * d + 1]);
          icpt[s]  = ic[s] + (double)pb[s * 3072 + 3 * d + 2];
        }
        ntv = nt + (double)nb[d];
      }
      #pragma unroll
      for (int s = 0; s < SSEG; s++) lg[s] += (double)pb[s * 3072 + 3 * d];

      double mx = -1e300;
      #pragma unroll
      for (int s = 0; s < SSEG; s++) mx = fmax(mx, lg[s]);
      double ew[10], ws = 0.0;
      #pragma unroll
      for (int s = 0; s < SSEG; s++) { ew[s] = exp(lg[s] - mx); ws += ew[s]; }

      double kp[11];
      kp[0] = -1.0;
      double cum = 0.0;
      #pragma unroll
      for (int s = 0; s < SSEG; s++) { cum += ew[s] / ws; kp[s + 1] = cum * 2.0 - 1.0; }

      double tt = (double)t[b];
      double vf[10], resid[10], lm = 0.0, rm = 0.0, integ = 0.0;
      #pragma unroll
      for (int s = 0; s < SSEG; s++) {
        double st = kp[s], en = kp[s + 1];
        bool v = ((tt >= st) && (tt < en)) || ((tt == 1.0) && (en == 1.0));
        double vv = v ? 1.0 : 0.0;
        vf[s] = vv;
        resid[s] = slope[s] * tt + icpt[s];
        lm += (tt - st) * vv;
        rm += (en - tt) * vv;
        integ += 0.5 * slope[s] * (en * en - st * st) + icpt[s] * (ew[s] / ws);
      }
      double rLV = 0.0, rV = 0.0, rRV = 0.0;
      #pragma unroll
      for (int s = 0; s < SSEG; s++) {
        double lv = (s == 0) ? vf[0] : vf[s - 1];
        double rv = (s == 9) ? vf[9] : vf[s + 1];
        rLV += resid[s] * lv;
        rV  += resid[s] * vf[s];
        rRV += resid[s] * rv;
      }
      double lw = 1.0 / (1.0 + exp(50.0 * lm));
      double rw = 1.0 / (1.0 + exp(50.0 * rm));
      double res = lw * rLV + (1.0 - lw - rw) * rV + rw * rRV - 0.5 * integ + ntv;
      out[(size_t)b * DOUT + d] = (float)res;
    }
  }
}

// ---------------------------------------------------------------------------
extern "C" void kernel_launch(void* const* d_in, const int* in_sizes, int n_in,
                              void* d_out, int out_size, void* d_ws, size_t ws_size,
                              hipStream_t stream) {
  const float* x  = (const float*)d_in[0];
  const float* t  = (const float*)d_in[1];
  const float* pW = (const float*)d_in[2];
  const float* pb = (const float*)d_in[3];
  const float* nW = (const float*)d_in[4];
  const float* nb = (const float*)d_in[5];
  float* out = (float*)d_out;

  // workspace layout (counter+worklist first so the fallback works with tiny ws)
  const size_t o_cnt = 0;
  const size_t o_wl  = 64;
  const size_t o_xh  = o_wl  + (size_t)WL_CAP * 4;         //  4 MiB
  const size_t o_xl  = o_xh  + (size_t)BS * DIN * 2;       //  4 MiB
  const size_t o_wsm = o_xl  + (size_t)BS * DIN * 2;       // 44 MiB (NCOL2 fp16)
  const size_t o_wh  = o_wsm + (size_t)NCOL2 * DIN * 2;    // 20 MiB
  const size_t o_wlo = o_wh  + (size_t)NLG * DIN * 2;      // 20 MiB
  const size_t o_wlt = o_wlo + (size_t)NLG * DIN * 2;      // 40 MiB (fp32 logit W^T)
  const size_t o_p   = o_wlt + (size_t)NLG * DIN * 4;      // 88 MiB (fp16 P2)
  const size_t o_lg  = o_p   + (size_t)BS * NCOL2 * 2;     // 84 MiB
  const size_t need  = o_lg  + (size_t)BS * NLG * 4;       // ~308 MiB total

  bool have_wl = ws_size >= 1024 * 1024;
  unsigned* cnt = (unsigned*)((char*)d_ws + o_cnt);
  unsigned* wl  = (unsigned*)((char*)d_ws + o_wl);
  unsigned cap  = 0;
  if (have_wl) {
    size_t avail = (ws_size >= need) ? (size_t)WL_CAP
                                     : (ws_size - o_wl) / 4;
    cap = (unsigned)(avail < WL_CAP ? avail : WL_CAP);
  }

  if (ws_size >= need) {
    half_t* xh  = (half_t*)((char*)d_ws + o_xh);
    half_t* xl  = (half_t*)((char*)d_ws + o_xl);
    half_t* wsm = (half_t*)((char*)d_ws + o_wsm);
    half_t* wh  = (half_t*)((char*)d_ws + o_wh);
    half_t* wlo = (half_t*)((char*)d_ws + o_wlo);
    float*  wlt = (float*)((char*)d_ws + o_wlt);
    half_t* P   = (half_t*)((char*)d_ws + o_p);
    float*  Lg  = (float*)((char*)d_ws + o_lg);

    k_split_x<<<(BS * DIN) / 1024, 256, 0, stream>>>(x, xh, xl, cnt);
    k_transw<<<dim3(NPAR / 384, DIN / 32), 256, 0, stream>>>(pW, wsm, wh, wlo, wlt);
    k_transpose<<<dim3(DOUT / 32, DIN / 32), 256, 0, stream>>>(nW, wsm, DOUT, NPK);
    k_gemm_all<<<dim3(NT_LG + NT_SM, BS / 128), 256, 0, stream>>>(xh, xl, wsm, wh, wlo,
                                                                  P, Lg, pb, nb);
    k_pointwise<<<dim3(BS, DOUT / 256), 256, 0, stream>>>(P, Lg, t, out, cnt,
                                                          have_wl ? wl : nullptr, cap);
    if (have_wl)
      k_redo<<<256, 256, 0, stream>>>(x, t, pW, pb, nW, nb, P, wlt, 1, cnt, wl, cap, out);
  } else {
    if (have_wl) k_zero<<<1, 64, 0, stream>>>(cnt);
    k_naive<<<dim3(BS, DOUT / 256), 256, 0, stream>>>(x, t, pW, pb, nW, nb, out, cnt,
                                                      have_wl ? wl : nullptr, cap);
    if (have_wl)
      k_redo<<<256, 256, 0, stream>>>(x, t, pW, pb, nW, nb, nullptr, nullptr, 0,
                                      cnt, wl, cap, out);
  }
}

// Round 5
// 626.935 us; speedup vs baseline: 2.6615x; 1.0047x over previous
//
#include <hip/hip_runtime.h>
#include <cstdint>
#include <cstddef>

// Problem constants (fixed by the reference setup)
#define BS    2048
#define DIN   1024
#define DOUT  1024
#define SSEG  10
#define NPAR  30720          // dout * S * 3
#define NPK   20480          // packed smooth cols: S*DOUT*2 (ch1,ch2)
#define NCOL2 21504          // NPK + DOUT (norm appended)
#define NLG   10240          // S * DOUT logit columns (channel 0)
#define NT_LG 80             // logit n-tiles (first in merged GEMM ordering)
#define NT_SM 168            // smooth n-tiles
#define NT_ALL 248
#define MT    16             // m-tiles (BS/128)
#define TAU   5e-5f          // near-boundary radius (~10x worst fp32-pipeline kp error)
#define WL_CAP 1048576u      // worklist capacity (entries)

typedef _Float16 half_t;
typedef __attribute__((ext_vector_type(8))) _Float16 half8;
typedef __attribute__((ext_vector_type(4))) _Float16 half4;
typedef __attribute__((ext_vector_type(2))) _Float16 half2v;
typedef __attribute__((ext_vector_type(4))) float   floatx4;

__device__ __forceinline__ void gload16(const void* g, void* l) {
  __builtin_amdgcn_global_load_lds(
      (const __attribute__((address_space(1))) void*)g,
      (__attribute__((address_space(3))) void*)l, 16, 0, 0);
}

// ---------------------------------------------------------------------------
__global__ void k_zero(unsigned* c) { if (threadIdx.x == 0) *c = 0; }

// ---------------------------------------------------------------------------
// x (fp32) -> xh = fp16(x), xl = fp16(x - xh). Also zeroes the worklist cnt.
// ---------------------------------------------------------------------------
__global__ __launch_bounds__(256) void k_split_x(const float* __restrict__ x,
                                                 half_t* __restrict__ xh,
                                                 half_t* __restrict__ xl,
                                                 unsigned* __restrict__ cnt) {
  if (blockIdx.x == 0 && threadIdx.x == 0) *cnt = 0;
  int i = blockIdx.x * 256 + threadIdx.x;      // float4 groups
  floatx4 v = ((const floatx4*)x)[i];
  half4 h, l;
  #pragma unroll
  for (int c = 0; c < 4; c++) { h[c] = (half_t)v[c]; l[c] = (half_t)(v[c] - (float)h[c]); }
  ((half4*)xh)[i] = h;
  ((half4*)xl)[i] = l;
}

// ---------------------------------------------------------------------------
// Merged W transpose: one coalesced pass over param_W emitting
//  - wsm  [NPK][DIN] fp16 : packed ch1/ch2 (col s*2048+2d+c)
//  - wh/wlo [NLG][DIN] fp16x2 of 32*w (logit cols, col s*1024+d)
//  - wlt  [NLG][DIN] fp32 exact logit weights (for coalesced f64 redo)
// Block: 32 k-rows x 384 src cols (= 128 d x 3ch, s fixed since 384|3072).
// ---------------------------------------------------------------------------
__global__ __launch_bounds__(256) void k_transw(const float* __restrict__ src,
                                                half_t* __restrict__ wsm,
                                                half_t* __restrict__ wh,
                                                half_t* __restrict__ wlo,
                                                float* __restrict__ wlt) {
  __shared__ float tile[32][384];
  int bx = blockIdx.x;                 // 0..79
  int k0 = blockIdx.y * 32;
  int tid = threadIdx.x;
  int s  = bx >> 3;                    // logit segment (3072-col group)
  int d0 = (bx & 7) * 128;
  const float* sb = src + (size_t)k0 * NPAR + bx * 384;
  for (int i = tid; i < 32 * 96; i += 256) {     // 12 fully-coalesced float4/thread
    int r = i / 96, q = i - r * 96;
    ((floatx4*)&tile[r][0])[q] = ((const floatx4*)(sb + (size_t)r * NPAR))[q];
  }
  __syncthreads();
  int j   = tid & 127;                 // d offset
  int ks  = (tid >> 7) * 16;           // k half-segment
  // ch0 -> wh/wlo/wlt (LDS col reads: bank (3j)%32, 2-way alias = free)
  {
    size_t row = (size_t)(s * 1024 + d0 + j) * DIN + k0 + ks;
    #pragma unroll
    for (int m = 0; m < 16; m++) {
      float raw = tile[ks + m][3 * j];
      float v = raw * 32.0f;           // exact pow2 scale keeps lo part normal
      half_t h = (half_t)v;
      wlt[row + m] = raw;
      wh [row + m] = h;
      wlo[row + m] = (half_t)(v - (float)h);
    }
  }
  // ch1/ch2 -> wsm
  #pragma unroll
  for (int c = 0; c < 2; c++) {
    size_t row = (size_t)(s * 2048 + 2 * (d0 + j) + c) * DIN + k0 + ks;
    #pragma unroll
    for (int m = 0; m < 16; m++)
      wsm[row + m] = (half_t)tile[ks + m][3 * j + 1 + c];
  }
}

// ---------------------------------------------------------------------------
// Norm transpose: norm_W -> wsm rows [NPK, NCOL2)
// ---------------------------------------------------------------------------
__global__ __launch_bounds__(256) void k_transpose(const float* __restrict__ src,
                                                   half_t* __restrict__ dst,
                                                   int ncols, int col_off) {
  __shared__ float tile[32][33];
  int tx = threadIdx.x & 31;
  int ty = threadIdx.x >> 5;
  int col0 = blockIdx.x * 32;
  int k0   = blockIdx.y * 32;
  #pragma unroll
  for (int r = ty; r < 32; r += 8)
    tile[r][tx] = src[(size_t)(k0 + r) * ncols + col0 + tx];
  __syncthreads();
  #pragma unroll
  for (int r = ty; r < 32; r += 8)
    dst[(size_t)(col0 + r + col_off) * DIN + k0 + tx] = (half_t)tile[tx][r];
}

// ---------------------------------------------------------------------------
// Merged GEMM, 1-D grid with supertile swizzle for LLC weight reuse:
//   chunk = 8 n-tiles x all 16 m-tiles (128 blocks, m fastest). Resident
//   blocks then share a ~30 MB weight window + 8 MB A -> each weight byte
//   fetched from HBM once (fixes the 689 MB overfetch of the (248,16) grid).
// n-tiles [0,80): logit fp16x2 3-pass -> Lg fp32.
// n-tiles [80,248): smooth 1-pass -> P fp16 (+bias).
// ---------------------------------------------------------------------------
__global__ __launch_bounds__(256) void k_gemm_all(const half_t* __restrict__ Ah,
                                                  const half_t* __restrict__ Al,
                                                  const half_t* __restrict__ Wsm,
                                                  const half_t* __restrict__ Bh,
                                                  const half_t* __restrict__ Bl,
                                                  half_t* __restrict__ P,
                                                  float* __restrict__ Lg,
                                                  const float* __restrict__ pb,
                                                  const float* __restrict__ nb) {
  __shared__ __attribute__((aligned(16))) half_t s0[128 * 32];
  __shared__ __attribute__((aligned(16))) half_t s1[128 * 32];
  __shared__ __attribute__((aligned(16))) half_t s2[128 * 32];
  __shared__ __attribute__((aligned(16))) half_t s3[128 * 32];
  const int K = DIN;
  int bid = blockIdx.x;                // 0..3967
  int chunk  = bid >> 7;               // 31 chunks of (16 m x 8 n)
  int within = bid & 127;
  int mt = within & 15;                // m fastest: same-n blocks adjacent
  int nt = chunk * 8 + (within >> 4);
  int m0 = mt * 128;
  int tid = threadIdx.x, w = tid >> 6, L = tid & 63;
  int wm = (w >> 1) * 64, wn = (w & 1) * 64;
  int l15 = L & 15, quad = L >> 4;

  size_t arow = (size_t)(m0 + w * 16 + (L >> 2)) * K + (L & 3) * 8;
  char* l0 = (char*)s0 + w * 1024;
  char* l1 = (char*)s1 + w * 1024;
  char* l2 = (char*)s2 + w * 1024;
  char* l3 = (char*)s3 + w * 1024;

  floatx4 acc[4][4] = {};

  if (nt < NT_LG) {
    // ---- logit region: fp16x2, 3 MFMA passes ----
    int n0 = nt * 128;
    size_t brow = (size_t)(n0 + w * 16 + (L >> 2)) * K + (L & 3) * 8;

    for (int k0 = 0; k0 < K; k0 += 32) {
      __syncthreads();
      gload16(Ah + arow + k0,          l0);
      gload16(Ah + arow + 64 * K + k0, l0 + 4096);
      gload16(Al + arow + k0,          l1);
      gload16(Al + arow + 64 * K + k0, l1 + 4096);
      gload16(Bh + brow + k0,          l2);
      gload16(Bh + brow + 64 * K + k0, l2 + 4096);
      gload16(Bl + brow + k0,          l3);
      gload16(Bl + brow + 64 * K + k0, l3 + 4096);
      __syncthreads();

      #pragma unroll
      for (int mi = 0; mi < 4; mi++) {
        half8 afh = *(const half8*)((const char*)s0 + (wm + mi * 16 + l15) * 64 + quad * 16);
        half8 afl = *(const half8*)((const char*)s1 + (wm + mi * 16 + l15) * 64 + quad * 16);
        #pragma unroll
        for (int ni = 0; ni < 4; ni++) {
          half8 bfh = *(const half8*)((const char*)s2 + (wn + ni * 16 + l15) * 64 + quad * 16);
          half8 bfl = *(const half8*)((const char*)s3 + (wn + ni * 16 + l15) * 64 + quad * 16);
          floatx4 a = acc[mi][ni];
          a = __builtin_amdgcn_mfma_f32_16x16x32_f16(afh, bfh, a, 0, 0, 0);
          a = __builtin_amdgcn_mfma_f32_16x16x32_f16(afl, bfh, a, 0, 0, 0);
          a = __builtin_amdgcn_mfma_f32_16x16x32_f16(afh, bfl, a, 0, 0, 0);
          acc[mi][ni] = a;
        }
      }
    }

    #pragma unroll
    for (int ni = 0; ni < 4; ni++) {
      int col = n0 + wn + ni * 16 + l15;                     // packed s*1024+d
      float bias = pb[(col >> 10) * 3072 + (col & 1023) * 3];
      #pragma unroll
      for (int mi = 0; mi < 4; mi++) {
        int row = m0 + wm + mi * 16 + quad * 4;
        floatx4 v = acc[mi][ni];
        #pragma unroll
        for (int r = 0; r < 4; r++)
          Lg[(size_t)(row + r) * NLG + col] = v[r] * 0.03125f + bias;
      }
    }
  } else {
    // ---- smooth region: plain fp16, 1 pass ----
    int n0 = (nt - NT_LG) * 128;
    size_t brow = (size_t)(n0 + w * 16 + (L >> 2)) * K + (L & 3) * 8;

    for (int k0 = 0; k0 < K; k0 += 32) {
      __syncthreads();
      gload16(Ah + arow + k0,           l0);
      gload16(Ah + arow + 64 * K + k0,  l0 + 4096);
      gload16(Wsm + brow + k0,          l2);
      gload16(Wsm + brow + 64 * K + k0, l2 + 4096);
      __syncthreads();

      half8 af[4], bf[4];
      #pragma unroll
      for (int mi = 0; mi < 4; mi++)
        af[mi] = *(const half8*)((const char*)s0 + (wm + mi * 16 + l15) * 64 + quad * 16);
      #pragma unroll
      for (int ni = 0; ni < 4; ni++)
        bf[ni] = *(const half8*)((const char*)s2 + (wn + ni * 16 + l15) * 64 + quad * 16);
      #pragma unroll
      for (int mi = 0; mi < 4; mi++)
        #pragma unroll
        for (int ni = 0; ni < 4; ni++)
          acc[mi][ni] = __builtin_amdgcn_mfma_f32_16x16x32_f16(af[mi], bf[ni], acc[mi][ni], 0, 0, 0);
    }

    #pragma unroll
    for (int ni = 0; ni < 4; ni++) {
      int col = n0 + wn + ni * 16 + l15;
      float bias;
      if (col < NPK) {
        int s = col >> 11, rem = col & 2047;
        bias = pb[s * 3072 + 3 * (rem >> 1) + 1 + (rem & 1)];
      } else {
        bias = nb[col - NPK];
      }
      #pragma unroll
      for (int mi = 0; mi < 4; mi++) {
        int row = m0 + wm + mi * 16 + quad * 4;
        floatx4 v = acc[mi][ni];
        #pragma unroll
        for (int r = 0; r < 4; r++)
          P[(size_t)(row + r) * NCOL2 + col] = (half_t)(v[r] + bias);
      }
    }
  }
}

// ---------------------------------------------------------------------------
// fp32 formula; mind = min_j |t - kp[j]| for near-boundary flagging
// ---------------------------------------------------------------------------
__device__ __forceinline__ float spiking_eval(const float* p, float tt, float* mind) {
  float mx = -1e30f;
  #pragma unroll
  for (int s = 0; s < SSEG; s++) mx = fmaxf(mx, p[3 * s]);
  float ew[10], wsum = 0.0f;
  #pragma unroll
  for (int s = 0; s < SSEG; s++) { ew[s] = __expf(p[3 * s] - mx); wsum += ew[s]; }
  float inv = 1.0f / wsum;

  float kp[11];
  kp[0] = -1.0f;
  float cum = 0.0f, md = 1e30f;
  #pragma unroll
  for (int s = 0; s < SSEG; s++) {
    cum += ew[s] * inv;
    kp[s + 1] = cum * 2.0f - 1.0f;
    md = fminf(md, fabsf(tt - kp[s + 1]));
  }
  *mind = md;

  float vf[10], resid[10];
  float lm = 0.0f, rm = 0.0f, integ = 0.0f;
  #pragma unroll
  for (int s = 0; s < SSEG; s++) {
    float p1 = p[3 * s + 1], p2 = p[3 * s + 2];
    float e2 = __expf(2.0f * fabsf(p1));
    float th = copysignf(1.0f - 2.0f / (e2 + 1.0f), p1);
    resid[s] = th * tt + p2;
    float st = kp[s], en = kp[s + 1];
    bool v = ((tt >= st) && (tt < en)) || ((tt == 1.0f) && (en == 1.0f));
    float vv = v ? 1.0f : 0.0f;
    vf[s] = vv;
    lm += (tt - st) * vv;
    rm += (en - tt) * vv;
    integ += 0.5f * th * (en * en - st * st) + p2 * (ew[s] * inv);
  }
  float resLV = 0.0f, resV = 0.0f, resRV = 0.0f;
  #pragma unroll
  for (int s = 0; s < SSEG; s++) {
    float lv = (s == 0) ? vf[0] : vf[s - 1];
    float rv = (s == 9) ? vf[9] : vf[s + 1];
    resLV += resid[s] * lv;
    resV  += resid[s] * vf[s];
    resRV += resid[s] * rv;
  }
  float lw = 1.0f / (1.0f + __expf(50.0f * lm));
  float rw = 1.0f / (1.0f + __expf(50.0f * rm));
  float swt = 1.0f - lw - rw;
  return lw * resLV + swt * resV + rw * resRV - 0.5f * integ + p[30];
}

// ---------------------------------------------------------------------------
// Pointwise: logits fp32 from Lg, ch1/2+norm fp16 from P. Flags near-boundary.
// ---------------------------------------------------------------------------
__global__ __launch_bounds__(256) void k_pointwise(const half_t* __restrict__ P,
                                                   const float* __restrict__ Lg,
                                                   const float* __restrict__ t,
                                                   float* __restrict__ out,
                                                   unsigned* __restrict__ cnt,
                                                   unsigned* __restrict__ wl,
                                                   unsigned cap) {
  __shared__ __attribute__((aligned(16))) half_t sp[SSEG * 512];
  int b = blockIdx.x, dg = blockIdx.y, tid = threadIdx.x;
  const half_t* Pb = P + (size_t)b * NCOL2;
  for (int i = tid; i < SSEG * 64; i += 256) {     // 640 x 16B
    int s = i >> 6, e = i & 63;
    ((uint4*)sp)[(s << 6) + e] = ((const uint4*)(Pb + s * 2048 + dg * 512))[e];
  }
  float tt = t[b];
  float nt = (float)Pb[NPK + dg * 256 + tid];
  const float* Lb = Lg + (size_t)b * NLG + dg * 256 + tid;
  __syncthreads();

  float p[31];
  #pragma unroll
  for (int s = 0; s < SSEG; s++) {
    p[3 * s] = Lb[s * 1024];                       // accurate logit (bias incl.)
    half2v hv = ((const half2v*)sp)[s * 256 + tid];  // 4B/lane, conflict-free
    p[3 * s + 1] = (float)hv.x;
    p[3 * s + 2] = (float)hv.y;
  }
  p[30] = nt;
  float mind;
  float r = spiking_eval(p, tt, &mind);
  int d = dg * 256 + tid;
  out[(size_t)b * DOUT + d] = r;
  if (wl != nullptr && mind < TAU) {
    unsigned idx = atomicAdd(cnt, 1u);
    if (idx < cap) wl[idx] = ((unsigned)b << 10) | (unsigned)d;
  }
}

// ---------------------------------------------------------------------------
// Fallback: fused naive fp32 + flagging (tiny-workspace insurance)
// ---------------------------------------------------------------------------
__global__ __launch_bounds__(256) void k_naive(const float* __restrict__ x,
                                               const float* __restrict__ t,
                                               const float* __restrict__ pW,
                                               const float* __restrict__ pb,
                                               const float* __restrict__ nW,
                                               const float* __restrict__ nb,
                                               float* __restrict__ out,
                                               unsigned* __restrict__ cnt,
                                               unsigned* __restrict__ wl,
                                               unsigned cap) {
  __shared__ float xs[DIN];
  int b = blockIdx.x, dg = blockIdx.y, tid = threadIdx.x;
  for (int i = tid; i < DIN; i += 256) xs[i] = x[(size_t)b * DIN + i];
  __syncthreads();
  int d = dg * 256 + tid;
  float acc[31];
  #pragma unroll
  for (int i = 0; i < 31; i++) acc[i] = 0.0f;
  for (int k = 0; k < DIN; k++) {
    float xv = xs[k];
    const float* wr = pW + (size_t)k * NPAR + 3 * d;
    #pragma unroll
    for (int s = 0; s < SSEG; s++) {
      acc[3 * s]     += xv * wr[s * 3072];
      acc[3 * s + 1] += xv * wr[s * 3072 + 1];
      acc[3 * s + 2] += xv * wr[s * 3072 + 2];
    }
    acc[30] += xv * nW[(size_t)k * DOUT + d];
  }
  #pragma unroll
  for (int s = 0; s < SSEG; s++) {
    acc[3 * s]     += pb[s * 3072 + 3 * d];
    acc[3 * s + 1] += pb[s * 3072 + 3 * d + 1];
    acc[3 * s + 2] += pb[s * 3072 + 3 * d + 2];
  }
  acc[30] += nb[d];
  float mind;
  float r = spiking_eval(acc, t[b], &mind);
  out[(size_t)b * DOUT + d] = r;
  if (wl != nullptr && mind < TAU) {
    unsigned idx = atomicAdd(cnt, 1u);
    if (idx < cap) wl[idx] = ((unsigned)b << 10) | (unsigned)d;
  }
}

// ---------------------------------------------------------------------------
// f64 redo: one wave per flagged (b,d). haveP: coalesced WLt logit weights +
// fp16 smooth channels from P. !haveP: pW gather (fallback path).
// ---------------------------------------------------------------------------
__global__ __launch_bounds__(256) void k_redo(const float* __restrict__ x,
                                              const float* __restrict__ t,
                                              const float* __restrict__ pW,
                                              const float* __restrict__ pb,
                                              const float* __restrict__ nW,
                                              const float* __restrict__ nb,
                                              const half_t* __restrict__ P,
                                              const float* __restrict__ WLt,
                                              int haveP,
                                              const unsigned* __restrict__ cnt,
                                              const unsigned* __restrict__ wl,
                                              unsigned cap,
                                              float* __restrict__ out) {
  unsigned n = *cnt;
  if (n > cap) n = cap;
  int lane = threadIdx.x & 63;
  unsigned wave = (blockIdx.x * 256 + threadIdx.x) >> 6;
  unsigned nwaves = (gridDim.x * 256) >> 6;

  for (unsigned e = wave; e < n; e += nwaves) {
    unsigned code = wl[e];
    int b = (int)(code >> 10), d = (int)(code & 1023);

    double lg[10], sl[10], ic[10], nt = 0.0;
    #pragma unroll
    for (int s = 0; s < SSEG; s++) { lg[s] = 0.0; sl[s] = 0.0; ic[s] = 0.0; }

    if (haveP) {
      for (int k = lane; k < DIN; k += 64) {     // coalesced WLt rows
        double xv = (double)x[(size_t)b * DIN + k];
        #pragma unroll
        for (int s = 0; s < SSEG; s++)
          lg[s] += xv * (double)WLt[(size_t)(s * 1024 + d) * DIN + k];
      }
    } else {
      for (int k = lane; k < DIN; k += 64) {
        double xv = (double)x[(size_t)b * DIN + k];
        const float* wr = pW + (size_t)k * NPAR + 3 * d;
        #pragma unroll
        for (int s = 0; s < SSEG; s++) {
          lg[s] += xv * (double)wr[s * 3072];
          sl[s] += xv * (double)wr[s * 3072 + 1];
          ic[s] += xv * (double)wr[s * 3072 + 2];
        }
        nt += xv * (double)nW[(size_t)k * DOUT + d];
      }
    }
    #pragma unroll
    for (int off = 32; off > 0; off >>= 1) {
      #pragma unroll
      for (int s = 0; s < SSEG; s++) lg[s] += __shfl_down(lg[s], off);
      if (!haveP) {
        #pragma unroll
        for (int s = 0; s < SSEG; s++) {
          sl[s] += __shfl_down(sl[s], off);
          ic[s] += __shfl_down(ic[s], off);
        }
        nt += __shfl_down(nt, off);
      }
    }

    if (lane == 0) {
      double slope[10], icpt[10], ntv;
      if (haveP) {
        const half_t* Pr = P + (size_t)b * NCOL2;
        #pragma unroll
        for (int s = 0; s < SSEG; s++) {
          slope[s] = tanh((double)(float)Pr[s * 2048 + 2 * d]);
          icpt[s]  = (double)(float)Pr[s * 2048 + 2 * d + 1];
        }
        ntv = (double)(float)Pr[NPK + d];
      } else {
        #pragma unroll
        for (int s = 0; s < SSEG; s++) {
          slope[s] = tanh(sl[s] + (double)pb[s * 3072 + 3 * d + 1]);
          icpt[s]  = ic[s] + (double)pb[s * 3072 + 3 * d + 2];
        }
        ntv = nt + (double)nb[d];
      }
      #pragma unroll
      for (int s = 0; s < SSEG; s++) lg[s] += (double)pb[s * 3072 + 3 * d];

      double mx = -1e300;
      #pragma unroll
      for (int s = 0; s < SSEG; s++) mx = fmax(mx, lg[s]);
      double ew[10], ws = 0.0;
      #pragma unroll
      for (int s = 0; s < SSEG; s++) { ew[s] = exp(lg[s] - mx); ws += ew[s]; }

      double kp[11];
      kp[0] = -1.0;
      double cum = 0.0;
      #pragma unroll
      for (int s = 0; s < SSEG; s++) { cum += ew[s] / ws; kp[s + 1] = cum * 2.0 - 1.0; }

      double tt = (double)t[b];
      double vf[10], resid[10], lm = 0.0, rm = 0.0, integ = 0.0;
      #pragma unroll
      for (int s = 0; s < SSEG; s++) {
        double st = kp[s], en = kp[s + 1];
        bool v = ((tt >= st) && (tt < en)) || ((tt == 1.0) && (en == 1.0));
        double vv = v ? 1.0 : 0.0;
        vf[s] = vv;
        resid[s] = slope[s] * tt + icpt[s];
        lm += (tt - st) * vv;
        rm += (en - tt) * vv;
        integ += 0.5 * slope[s] * (en * en - st * st) + icpt[s] * (ew[s] / ws);
      }
      double rLV = 0.0, rV = 0.0, rRV = 0.0;
      #pragma unroll
      for (int s = 0; s < SSEG; s++) {
        double lv = (s == 0) ? vf[0] : vf[s - 1];
        double rv = (s == 9) ? vf[9] : vf[s + 1];
        rLV += resid[s] * lv;
        rV  += resid[s] * vf[s];
        rRV += resid[s] * rv;
      }
      double lw = 1.0 / (1.0 + exp(50.0 * lm));
      double rw = 1.0 / (1.0 + exp(50.0 * rm));
      double res = lw * rLV + (1.0 - lw - rw) * rV + rw * rRV - 0.5 * integ + ntv;
      out[(size_t)b * DOUT + d] = (float)res;
    }
  }
}

// ---------------------------------------------------------------------------
extern "C" void kernel_launch(void* const* d_in, const int* in_sizes, int n_in,
                              void* d_out, int out_size, void* d_ws, size_t ws_size,
                              hipStream_t stream) {
  const float* x  = (const float*)d_in[0];
  const float* t  = (const float*)d_in[1];
  const float* pW = (const float*)d_in[2];
  const float* pb = (const float*)d_in[3];
  const float* nW = (const float*)d_in[4];
  const float* nb = (const float*)d_in[5];
  float* out = (float*)d_out;

  // workspace layout (counter+worklist first so the fallback works with tiny ws)
  const size_t o_cnt = 0;
  const size_t o_wl  = 64;
  const size_t o_xh  = o_wl  + (size_t)WL_CAP * 4;         //  4 MiB
  const size_t o_xl  = o_xh  + (size_t)BS * DIN * 2;       //  4 MiB
  const size_t o_wsm = o_xl  + (size_t)BS * DIN * 2;       // 44 MiB (NCOL2 fp16)
  const size_t o_wh  = o_wsm + (size_t)NCOL2 * DIN * 2;    // 20 MiB
  const size_t o_wlo = o_wh  + (size_t)NLG * DIN * 2;      // 20 MiB
  const size_t o_wlt = o_wlo + (size_t)NLG * DIN * 2;      // 40 MiB (fp32 logit W^T)
  const size_t o_p   = o_wlt + (size_t)NLG * DIN * 4;      // 88 MiB (fp16 P2)
  const size_t o_lg  = o_p   + (size_t)BS * NCOL2 * 2;     // 84 MiB
  const size_t need  = o_lg  + (size_t)BS * NLG * 4;       // ~308 MiB total

  bool have_wl = ws_size >= 1024 * 1024;
  unsigned* cnt = (unsigned*)((char*)d_ws + o_cnt);
  unsigned* wl  = (unsigned*)((char*)d_ws + o_wl);
  unsigned cap  = 0;
  if (have_wl) {
    size_t avail = (ws_size >= need) ? (size_t)WL_CAP
                                     : (ws_size - o_wl) / 4;
    cap = (unsigned)(avail < WL_CAP ? avail : WL_CAP);
  }

  if (ws_size >= need) {
    half_t* xh  = (half_t*)((char*)d_ws + o_xh);
    half_t* xl  = (half_t*)((char*)d_ws + o_xl);
    half_t* wsm = (half_t*)((char*)d_ws + o_wsm);
    half_t* wh  = (half_t*)((char*)d_ws + o_wh);
    half_t* wlo = (half_t*)((char*)d_ws + o_wlo);
    float*  wlt = (float*)((char*)d_ws + o_wlt);
    half_t* P   = (half_t*)((char*)d_ws + o_p);
    float*  Lg  = (float*)((char*)d_ws + o_lg);

    k_split_x<<<(BS * DIN) / 1024, 256, 0, stream>>>(x, xh, xl, cnt);
    k_transw<<<dim3(NPAR / 384, DIN / 32), 256, 0, stream>>>(pW, wsm, wh, wlo, wlt);
    k_transpose<<<dim3(DOUT / 32, DIN / 32), 256, 0, stream>>>(nW, wsm, DOUT, NPK);
    k_gemm_all<<<dim3(NT_ALL * MT), 256, 0, stream>>>(xh, xl, wsm, wh, wlo,
                                                      P, Lg, pb, nb);
    k_pointwise<<<dim3(BS, DOUT / 256), 256, 0, stream>>>(P, Lg, t, out, cnt,
                                                          have_wl ? wl : nullptr, cap);
    if (have_wl)
      k_redo<<<256, 256, 0, stream>>>(x, t, pW, pb, nW, nb, P, wlt, 1, cnt, wl, cap, out);
  } else {
    if (have_wl) k_zero<<<1, 64, 0, stream>>>(cnt);
    k_naive<<<dim3(BS, DOUT / 256), 256, 0, stream>>>(x, t, pW, pb, nW, nb, out, cnt,
                                                      have_wl ? wl : nullptr, cap);
    if (have_wl)
      k_redo<<<256, 256, 0, stream>>>(x, t, pW, pb, nW, nb, nullptr, nullptr, 0,
                                      cnt, wl, cap, out);
  }
}

// Round 6
// 618.185 us; speedup vs baseline: 2.6992x; 1.0142x over previous
//
#include <hip/hip_runtime.h>
#include <cstdint>
#include <cstddef>

// Problem constants (fixed by the reference setup)
#define BS    2048
#define DIN   1024
#define DOUT  1024
#define SSEG  10
#define NPAR  30720          // dout * S * 3
#define NPK   20480          // packed smooth cols: S*DOUT*2 (ch1,ch2)
#define NCOL2 21504          // NPK + DOUT (norm appended)
#define NLG   10240          // S * DOUT logit columns (channel 0)
#define NT_LG 80             // logit n-tiles
#define NT_SM 168            // smooth n-tiles
#define MT    16             // m-tiles (BS/128)
#define TAU   5e-5f          // near-boundary radius (~10x worst fp32-pipeline kp error)
#define WL_CAP 1048576u      // worklist capacity (entries)

typedef _Float16 half_t;
typedef __attribute__((ext_vector_type(8))) _Float16 half8;
typedef __attribute__((ext_vector_type(4))) _Float16 half4;
typedef __attribute__((ext_vector_type(2))) _Float16 half2v;
typedef __attribute__((ext_vector_type(4))) float   floatx4;

__device__ __forceinline__ void gload16(const void* g, void* l) {
  __builtin_amdgcn_global_load_lds(
      (const __attribute__((address_space(1))) void*)g,
      (__attribute__((address_space(3))) void*)l, 16, 0, 0);
}

// ---------------------------------------------------------------------------
__global__ void k_zero(unsigned* c) { if (threadIdx.x == 0) *c = 0; }

// ---------------------------------------------------------------------------
// Prep: blocks [0,2048): x -> xh/xl fp16x2 split (+ zero worklist counter).
//       blocks [2048,3072): norm_W transpose -> wsm rows [NPK, NCOL2).
// ---------------------------------------------------------------------------
__global__ __launch_bounds__(256) void k_prep(const float* __restrict__ x,
                                              half_t* __restrict__ xh,
                                              half_t* __restrict__ xl,
                                              const float* __restrict__ nW,
                                              half_t* __restrict__ wsm,
                                              unsigned* __restrict__ cnt) {
  int bid = blockIdx.x;
  if (bid < 2048) {
    if (bid == 0 && threadIdx.x == 0) *cnt = 0;
    int i = bid * 256 + threadIdx.x;           // float4 groups over BS*DIN
    floatx4 v = ((const floatx4*)x)[i];
    half4 h, l;
    #pragma unroll
    for (int c = 0; c < 4; c++) { h[c] = (half_t)v[c]; l[c] = (half_t)(v[c] - (float)h[c]); }
    ((half4*)xh)[i] = h;
    ((half4*)xl)[i] = l;
  } else {
    __shared__ float tile[32][33];
    int b2 = bid - 2048;                       // 0..1023
    int col0 = (b2 & 31) * 32;
    int k0   = (b2 >> 5) * 32;
    int tx = threadIdx.x & 31;
    int ty = threadIdx.x >> 5;
    #pragma unroll
    for (int r = ty; r < 32; r += 8)
      tile[r][tx] = nW[(size_t)(k0 + r) * DOUT + col0 + tx];
    __syncthreads();
    #pragma unroll
    for (int r = ty; r < 32; r += 8)
      wsm[(size_t)(col0 + r + NPK) * DIN + k0 + tx] = (half_t)tile[tx][r];
  }
}

// ---------------------------------------------------------------------------
// Merged W transpose: one coalesced pass over param_W emitting
//  - wsm  [NPK][DIN] fp16 : packed ch1/ch2 (col s*2048+2d+c)
//  - wh/wlo [NLG][DIN] fp16x2 of 32*w (logit cols, col s*1024+d)
//  - wlt  [NLG][DIN] fp32 exact logit weights (for coalesced f64 redo)
// ---------------------------------------------------------------------------
__global__ __launch_bounds__(256) void k_transw(const float* __restrict__ src,
                                                half_t* __restrict__ wsm,
                                                half_t* __restrict__ wh,
                                                half_t* __restrict__ wlo,
                                                float* __restrict__ wlt) {
  __shared__ float tile[32][384];
  int bx = blockIdx.x;                 // 0..79
  int k0 = blockIdx.y * 32;
  int tid = threadIdx.x;
  int s  = bx >> 3;                    // logit segment (3072-col group)
  int d0 = (bx & 7) * 128;
  const float* sb = src + (size_t)k0 * NPAR + bx * 384;
  for (int i = tid; i < 32 * 96; i += 256) {     // 12 fully-coalesced float4/thread
    int r = i / 96, q = i - r * 96;
    ((floatx4*)&tile[r][0])[q] = ((const floatx4*)(sb + (size_t)r * NPAR))[q];
  }
  __syncthreads();
  int j   = tid & 127;                 // d offset
  int ks  = (tid >> 7) * 16;           // k half-segment
  {
    size_t row = (size_t)(s * 1024 + d0 + j) * DIN + k0 + ks;
    #pragma unroll
    for (int m = 0; m < 16; m++) {
      float raw = tile[ks + m][3 * j];
      float v = raw * 32.0f;           // exact pow2 scale keeps lo part normal
      half_t h = (half_t)v;
      wlt[row + m] = raw;
      wh [row + m] = h;
      wlo[row + m] = (half_t)(v - (float)h);
    }
  }
  #pragma unroll
  for (int c = 0; c < 2; c++) {
    size_t row = (size_t)(s * 2048 + 2 * (d0 + j) + c) * DIN + k0 + ks;
    #pragma unroll
    for (int m = 0; m < 16; m++)
      wsm[row + m] = (half_t)tile[ks + m][3 * j + 1 + c];
  }
}

// ---------------------------------------------------------------------------
// XCD-exclusive swizzle (dispatch round-robins XCDs: xcd ~ bid & 7):
// all 16 m-blocks of one n-tile land consecutively on ONE XCD, so each B-tile
// is fetched into exactly one per-XCD L2 (kills the 4x cross-XCD dup fetch).
// ---------------------------------------------------------------------------
__device__ __forceinline__ void swizzle_mn(int bid, int* mt, int* nt) {
  int x = bid & 7;
  int g = bid >> 3;
  *mt = g & 15;
  *nt = (g >> 4) * 8 + x;
}

// ---------------------------------------------------------------------------
// Logit GEMM, fp16x2: Lg(BS x NLG fp32) = (xh+xl)(wh+wlo)^T/32 + bias
// (drops xl*wlo term). 1280 blocks, swizzled.
// ---------------------------------------------------------------------------
__global__ __launch_bounds__(256) void k_gemm_logit(const half_t* __restrict__ Ah,
                                                    const half_t* __restrict__ Al,
                                                    const half_t* __restrict__ Bh,
                                                    const half_t* __restrict__ Bl,
                                                    float* __restrict__ Lg,
                                                    const float* __restrict__ pb) {
  __shared__ __attribute__((aligned(16))) half_t sAh[128 * 32];
  __shared__ __attribute__((aligned(16))) half_t sAl[128 * 32];
  __shared__ __attribute__((aligned(16))) half_t sBh[128 * 32];
  __shared__ __attribute__((aligned(16))) half_t sBl[128 * 32];
  const int K = DIN;
  int mt, nt;
  swizzle_mn(blockIdx.x, &mt, &nt);
  int m0 = mt * 128, n0 = nt * 128;
  int tid = threadIdx.x, w = tid >> 6, L = tid & 63;
  int wm = (w >> 1) * 64, wn = (w & 1) * 64;
  int l15 = L & 15, quad = L >> 4;

  size_t arow = (size_t)(m0 + w * 16 + (L >> 2)) * K + (L & 3) * 8;
  size_t brow = (size_t)(n0 + w * 16 + (L >> 2)) * K + (L & 3) * 8;
  char* lah = (char*)sAh + w * 1024;
  char* lal = (char*)sAl + w * 1024;
  char* lbh = (char*)sBh + w * 1024;
  char* lbl = (char*)sBl + w * 1024;

  floatx4 acc[4][4] = {};

  for (int k0 = 0; k0 < K; k0 += 32) {
    __syncthreads();
    gload16(Ah + arow + k0,          lah);
    gload16(Ah + arow + 64 * K + k0, lah + 4096);
    gload16(Al + arow + k0,          lal);
    gload16(Al + arow + 64 * K + k0, lal + 4096);
    gload16(Bh + brow + k0,          lbh);
    gload16(Bh + brow + 64 * K + k0, lbh + 4096);
    gload16(Bl + brow + k0,          lbl);
    gload16(Bl + brow + 64 * K + k0, lbl + 4096);
    __syncthreads();

    #pragma unroll
    for (int mi = 0; mi < 4; mi++) {
      half8 afh = *(const half8*)((const char*)sAh + (wm + mi * 16 + l15) * 64 + quad * 16);
      half8 afl = *(const half8*)((const char*)sAl + (wm + mi * 16 + l15) * 64 + quad * 16);
      #pragma unroll
      for (int ni = 0; ni < 4; ni++) {
        half8 bfh = *(const half8*)((const char*)sBh + (wn + ni * 16 + l15) * 64 + quad * 16);
        half8 bfl = *(const half8*)((const char*)sBl + (wn + ni * 16 + l15) * 64 + quad * 16);
        floatx4 a = acc[mi][ni];
        a = __builtin_amdgcn_mfma_f32_16x16x32_f16(afh, bfh, a, 0, 0, 0);
        a = __builtin_amdgcn_mfma_f32_16x16x32_f16(afl, bfh, a, 0, 0, 0);
        a = __builtin_amdgcn_mfma_f32_16x16x32_f16(afh, bfl, a, 0, 0, 0);
        acc[mi][ni] = a;
      }
    }
  }

  #pragma unroll
  for (int ni = 0; ni < 4; ni++) {
    int col = n0 + wn + ni * 16 + l15;                       // packed s*1024+d
    float bias = pb[(col >> 10) * 3072 + (col & 1023) * 3];
    #pragma unroll
    for (int mi = 0; mi < 4; mi++) {
      int row = m0 + wm + mi * 16 + quad * 4;
      floatx4 v = acc[mi][ni];
      #pragma unroll
      for (int r = 0; r < 4; r++)
        Lg[(size_t)(row + r) * NLG + col] = v[r] * 0.03125f + bias;
    }
  }
}

// ---------------------------------------------------------------------------
// Smooth GEMM: P(BS x NCOL2, fp16) = xh * wsm^T + bias. 2688 blocks, swizzled.
// ---------------------------------------------------------------------------
__global__ __launch_bounds__(256) void k_gemm_sm(const half_t* __restrict__ A,
                                                 const half_t* __restrict__ B,
                                                 half_t* __restrict__ P,
                                                 const float* __restrict__ pb,
                                                 const float* __restrict__ nb) {
  __shared__ __attribute__((aligned(16))) half_t As[128 * 32];
  __shared__ __attribute__((aligned(16))) half_t Bs[128 * 32];
  const int K = DIN;
  int mt, nt;
  swizzle_mn(blockIdx.x, &mt, &nt);
  int m0 = mt * 128, n0 = nt * 128;
  int tid = threadIdx.x, w = tid >> 6, L = tid & 63;
  int wm = (w >> 1) * 64, wn = (w & 1) * 64;
  int l15 = L & 15, quad = L >> 4;

  const half_t* ga = A + (size_t)(m0 + w * 16 + (L >> 2)) * K + (L & 3) * 8;
  const half_t* gb = B + (size_t)(n0 + w * 16 + (L >> 2)) * K + (L & 3) * 8;
  char* lA = (char*)As + w * 1024;
  char* lB = (char*)Bs + w * 1024;

  floatx4 acc[4][4] = {};

  for (int k0 = 0; k0 < K; k0 += 32) {
    __syncthreads();
    gload16(ga + k0,          lA);
    gload16(ga + 64 * K + k0, lA + 4096);
    gload16(gb + k0,          lB);
    gload16(gb + 64 * K + k0, lB + 4096);
    __syncthreads();

    half8 af[4], bf[4];
    #pragma unroll
    for (int mi = 0; mi < 4; mi++)
      af[mi] = *(const half8*)((const char*)As + (wm + mi * 16 + l15) * 64 + quad * 16);
    #pragma unroll
    for (int ni = 0; ni < 4; ni++)
      bf[ni] = *(const half8*)((const char*)Bs + (wn + ni * 16 + l15) * 64 + quad * 16);
    #pragma unroll
    for (int mi = 0; mi < 4; mi++)
      #pragma unroll
      for (int ni = 0; ni < 4; ni++)
        acc[mi][ni] = __builtin_amdgcn_mfma_f32_16x16x32_f16(af[mi], bf[ni], acc[mi][ni], 0, 0, 0);
  }

  #pragma unroll
  for (int ni = 0; ni < 4; ni++) {
    int col = n0 + wn + ni * 16 + l15;
    float bias;
    if (col < NPK) {
      int s = col >> 11, rem = col & 2047;
      bias = pb[s * 3072 + 3 * (rem >> 1) + 1 + (rem & 1)];
    } else {
      bias = nb[col - NPK];
    }
    #pragma unroll
    for (int mi = 0; mi < 4; mi++) {
      int row = m0 + wm + mi * 16 + quad * 4;
      floatx4 v = acc[mi][ni];
      #pragma unroll
      for (int r = 0; r < 4; r++)
        P[(size_t)(row + r) * NCOL2 + col] = (half_t)(v[r] + bias);
    }
  }
}

// ---------------------------------------------------------------------------
// fp32 formula; mind = min_j |t - kp[j]| for near-boundary flagging
// ---------------------------------------------------------------------------
__device__ __forceinline__ float spiking_eval(const float* p, float tt, float* mind) {
  float mx = -1e30f;
  #pragma unroll
  for (int s = 0; s < SSEG; s++) mx = fmaxf(mx, p[3 * s]);
  float ew[10], wsum = 0.0f;
  #pragma unroll
  for (int s = 0; s < SSEG; s++) { ew[s] = __expf(p[3 * s] - mx); wsum += ew[s]; }
  float inv = 1.0f / wsum;

  float kp[11];
  kp[0] = -1.0f;
  float cum = 0.0f, md = 1e30f;
  #pragma unroll
  for (int s = 0; s < SSEG; s++) {
    cum += ew[s] * inv;
    kp[s + 1] = cum * 2.0f - 1.0f;
    md = fminf(md, fabsf(tt - kp[s + 1]));
  }
  *mind = md;

  float vf[10], resid[10];
  float lm = 0.0f, rm = 0.0f, integ = 0.0f;
  #pragma unroll
  for (int s = 0; s < SSEG; s++) {
    float p1 = p[3 * s + 1], p2 = p[3 * s + 2];
    float e2 = __expf(2.0f * fabsf(p1));
    float th = copysignf(1.0f - 2.0f / (e2 + 1.0f), p1);
    resid[s] = th * tt + p2;
    float st = kp[s], en = kp[s + 1];
    bool v = ((tt >= st) && (tt < en)) || ((tt == 1.0f) && (en == 1.0f));
    float vv = v ? 1.0f : 0.0f;
    vf[s] = vv;
    lm += (tt - st) * vv;
    rm += (en - tt) * vv;
    integ += 0.5f * th * (en * en - st * st) + p2 * (ew[s] * inv);
  }
  float resLV = 0.0f, resV = 0.0f, resRV = 0.0f;
  #pragma unroll
  for (int s = 0; s < SSEG; s++) {
    float lv = (s == 0) ? vf[0] : vf[s - 1];
    float rv = (s == 9) ? vf[9] : vf[s + 1];
    resLV += resid[s] * lv;
    resV  += resid[s] * vf[s];
    resRV += resid[s] * rv;
  }
  float lw = 1.0f / (1.0f + __expf(50.0f * lm));
  float rw = 1.0f / (1.0f + __expf(50.0f * rm));
  float swt = 1.0f - lw - rw;
  return lw * resLV + swt * resV + rw * resRV - 0.5f * integ + p[30];
}

// ---------------------------------------------------------------------------
// Pointwise: logits fp32 from Lg, ch1/2+norm fp16 from P. Flags near-boundary.
// ---------------------------------------------------------------------------
__global__ __launch_bounds__(256) void k_pointwise(const half_t* __restrict__ P,
                                                   const float* __restrict__ Lg,
                                                   const float* __restrict__ t,
                                                   float* __restrict__ out,
                                                   unsigned* __restrict__ cnt,
                                                   unsigned* __restrict__ wl,
                                                   unsigned cap) {
  __shared__ __attribute__((aligned(16))) half_t sp[SSEG * 512];
  int b = blockIdx.x, dg = blockIdx.y, tid = threadIdx.x;
  const half_t* Pb = P + (size_t)b * NCOL2;
  for (int i = tid; i < SSEG * 64; i += 256) {     // 640 x 16B
    int s = i >> 6, e = i & 63;
    ((uint4*)sp)[(s << 6) + e] = ((const uint4*)(Pb + s * 2048 + dg * 512))[e];
  }
  float tt = t[b];
  float nt = (float)Pb[NPK + dg * 256 + tid];
  const float* Lb = Lg + (size_t)b * NLG + dg * 256 + tid;
  __syncthreads();

  float p[31];
  #pragma unroll
  for (int s = 0; s < SSEG; s++) {
    p[3 * s] = Lb[s * 1024];                       // accurate logit (bias incl.)
    half2v hv = ((const half2v*)sp)[s * 256 + tid];  // 4B/lane, conflict-free
    p[3 * s + 1] = (float)hv.x;
    p[3 * s + 2] = (float)hv.y;
  }
  p[30] = nt;
  float mind;
  float r = spiking_eval(p, tt, &mind);
  int d = dg * 256 + tid;
  out[(size_t)b * DOUT + d] = r;
  if (wl != nullptr && mind < TAU) {
    unsigned idx = atomicAdd(cnt, 1u);
    if (idx < cap) wl[idx] = ((unsigned)b << 10) | (unsigned)d;
  }
}

// ---------------------------------------------------------------------------
// Fallback: fused naive fp32 + flagging (tiny-workspace insurance)
// ---------------------------------------------------------------------------
__global__ __launch_bounds__(256) void k_naive(const float* __restrict__ x,
                                               const float* __restrict__ t,
                                               const float* __restrict__ pW,
                                               const float* __restrict__ pb,
                                               const float* __restrict__ nW,
                                               const float* __restrict__ nb,
                                               float* __restrict__ out,
                                               unsigned* __restrict__ cnt,
                                               unsigned* __restrict__ wl,
                                               unsigned cap) {
  __shared__ float xs[DIN];
  int b = blockIdx.x, dg = blockIdx.y, tid = threadIdx.x;
  for (int i = tid; i < DIN; i += 256) xs[i] = x[(size_t)b * DIN + i];
  __syncthreads();
  int d = dg * 256 + tid;
  float acc[31];
  #pragma unroll
  for (int i = 0; i < 31; i++) acc[i] = 0.0f;
  for (int k = 0; k < DIN; k++) {
    float xv = xs[k];
    const float* wr = pW + (size_t)k * NPAR + 3 * d;
    #pragma unroll
    for (int s = 0; s < SSEG; s++) {
      acc[3 * s]     += xv * wr[s * 3072];
      acc[3 * s + 1] += xv * wr[s * 3072 + 1];
      acc[3 * s + 2] += xv * wr[s * 3072 + 2];
    }
    acc[30] += xv * nW[(size_t)k * DOUT + d];
  }
  #pragma unroll
  for (int s = 0; s < SSEG; s++) {
    acc[3 * s]     += pb[s * 3072 + 3 * d];
    acc[3 * s + 1] += pb[s * 3072 + 3 * d + 1];
    acc[3 * s + 2] += pb[s * 3072 + 3 * d + 2];
  }
  acc[30] += nb[d];
  float mind;
  float r = spiking_eval(acc, t[b], &mind);
  out[(size_t)b * DOUT + d] = r;
  if (wl != nullptr && mind < TAU) {
    unsigned idx = atomicAdd(cnt, 1u);
    if (idx < cap) wl[idx] = ((unsigned)b << 10) | (unsigned)d;
  }
}

// ---------------------------------------------------------------------------
// f64 redo: one wave per flagged (b,d). haveP: coalesced WLt logit weights +
// fp16 smooth channels from P. !haveP: pW gather (fallback path).
// ---------------------------------------------------------------------------
__global__ __launch_bounds__(256) void k_redo(const float* __restrict__ x,
                                              const float* __restrict__ t,
                                              const float* __restrict__ pW,
                                              const float* __restrict__ pb,
                                              const float* __restrict__ nW,
                                              const float* __restrict__ nb,
                                              const half_t* __restrict__ P,
                                              const float* __restrict__ WLt,
                                              int haveP,
                                              const unsigned* __restrict__ cnt,
                                              const unsigned* __restrict__ wl,
                                              unsigned cap,
                                              float* __restrict__ out) {
  unsigned n = *cnt;
  if (n > cap) n = cap;
  int lane = threadIdx.x & 63;
  unsigned wave = (blockIdx.x * 256 + threadIdx.x) >> 6;
  unsigned nwaves = (gridDim.x * 256) >> 6;

  for (unsigned e = wave; e < n; e += nwaves) {
    unsigned code = wl[e];
    int b = (int)(code >> 10), d = (int)(code & 1023);

    double lg[10], sl[10], ic[10], nt = 0.0;
    #pragma unroll
    for (int s = 0; s < SSEG; s++) { lg[s] = 0.0; sl[s] = 0.0; ic[s] = 0.0; }

    if (haveP) {
      for (int k = lane; k < DIN; k += 64) {     // coalesced WLt rows
        double xv = (double)x[(size_t)b * DIN + k];
        #pragma unroll
        for (int s = 0; s < SSEG; s++)
          lg[s] += xv * (double)WLt[(size_t)(s * 1024 + d) * DIN + k];
      }
    } else {
      for (int k = lane; k < DIN; k += 64) {
        double xv = (double)x[(size_t)b * DIN + k];
        const float* wr = pW + (size_t)k * NPAR + 3 * d;
        #pragma unroll
        for (int s = 0; s < SSEG; s++) {
          lg[s] += xv * (double)wr[s * 3072];
          sl[s] += xv * (double)wr[s * 3072 + 1];
          ic[s] += xv * (double)wr[s * 3072 + 2];
        }
        nt += xv * (double)nW[(size_t)k * DOUT + d];
      }
    }
    #pragma unroll
    for (int off = 32; off > 0; off >>= 1) {
      #pragma unroll
      for (int s = 0; s < SSEG; s++) lg[s] += __shfl_down(lg[s], off);
      if (!haveP) {
        #pragma unroll
        for (int s = 0; s < SSEG; s++) {
          sl[s] += __shfl_down(sl[s], off);
          ic[s] += __shfl_down(ic[s], off);
        }
        nt += __shfl_down(nt, off);
      }
    }

    if (lane == 0) {
      double slope[10], icpt[10], ntv;
      if (haveP) {
        const half_t* Pr = P + (size_t)b * NCOL2;
        #pragma unroll
        for (int s = 0; s < SSEG; s++) {
          slope[s] = tanh((double)(float)Pr[s * 2048 + 2 * d]);
          icpt[s]  = (double)(float)Pr[s * 2048 + 2 * d + 1];
        }
        ntv = (double)(float)Pr[NPK + d];
      } else {
        #pragma unroll
        for (int s = 0; s < SSEG; s++) {
          slope[s] = tanh(sl[s] + (double)pb[s * 3072 + 3 * d + 1]);
          icpt[s]  = ic[s] + (double)pb[s * 3072 + 3 * d + 2];
        }
        ntv = nt + (double)nb[d];
      }
      #pragma unroll
      for (int s = 0; s < SSEG; s++) lg[s] += (double)pb[s * 3072 + 3 * d];

      double mx = -1e300;
      #pragma unroll
      for (int s = 0; s < SSEG; s++) mx = fmax(mx, lg[s]);
      double ew[10], ws = 0.0;
      #pragma unroll
      for (int s = 0; s < SSEG; s++) { ew[s] = exp(lg[s] - mx); ws += ew[s]; }

      double kp[11];
      kp[0] = -1.0;
      double cum = 0.0;
      #pragma unroll
      for (int s = 0; s < SSEG; s++) { cum += ew[s] / ws; kp[s + 1] = cum * 2.0 - 1.0; }

      double tt = (double)t[b];
      double vf[10], resid[10], lm = 0.0, rm = 0.0, integ = 0.0;
      #pragma unroll
      for (int s = 0; s < SSEG; s++) {
        double st = kp[s], en = kp[s + 1];
        bool v = ((tt >= st) && (tt < en)) || ((tt == 1.0) && (en == 1.0));
        double vv = v ? 1.0 : 0.0;
        vf[s] = vv;
        resid[s] = slope[s] * tt + icpt[s];
        lm += (tt - st) * vv;
        rm += (en - tt) * vv;
        integ += 0.5 * slope[s] * (en * en - st * st) + icpt[s] * (ew[s] / ws);
      }
      double rLV = 0.0, rV = 0.0, rRV = 0.0;
      #pragma unroll
      for (int s = 0; s < SSEG; s++) {
        double lv = (s == 0) ? vf[0] : vf[s - 1];
        double rv = (s == 9) ? vf[9] : vf[s + 1];
        rLV += resid[s] * lv;
        rV  += resid[s] * vf[s];
        rRV += resid[s] * rv;
      }
      double lw = 1.0 / (1.0 + exp(50.0 * lm));
      double rw = 1.0 / (1.0 + exp(50.0 * rm));
      double res = lw * rLV + (1.0 - lw - rw) * rV + rw * rRV - 0.5 * integ + ntv;
      out[(size_t)b * DOUT + d] = (float)res;
    }
  }
}

// ---------------------------------------------------------------------------
extern "C" void kernel_launch(void* const* d_in, const int* in_sizes, int n_in,
                              void* d_out, int out_size, void* d_ws, size_t ws_size,
                              hipStream_t stream) {
  const float* x  = (const float*)d_in[0];
  const float* t  = (const float*)d_in[1];
  const float* pW = (const float*)d_in[2];
  const float* pb = (const float*)d_in[3];
  const float* nW = (const float*)d_in[4];
  const float* nb = (const float*)d_in[5];
  float* out = (float*)d_out;

  // workspace layout (counter+worklist first so the fallback works with tiny ws)
  const size_t o_cnt = 0;
  const size_t o_wl  = 64;
  const size_t o_xh  = o_wl  + (size_t)WL_CAP * 4;         //  4 MiB
  const size_t o_xl  = o_xh  + (size_t)BS * DIN * 2;       //  4 MiB
  const size_t o_wsm = o_xl  + (size_t)BS * DIN * 2;       // 44 MiB (NCOL2 fp16)
  const size_t o_wh  = o_wsm + (size_t)NCOL2 * DIN * 2;    // 20 MiB
  const size_t o_wlo = o_wh  + (size_t)NLG * DIN * 2;      // 20 MiB
  const size_t o_wlt = o_wlo + (size_t)NLG * DIN * 2;      // 40 MiB (fp32 logit W^T)
  const size_t o_p   = o_wlt + (size_t)NLG * DIN * 4;      // 88 MiB (fp16 P2)
  const size_t o_lg  = o_p   + (size_t)BS * NCOL2 * 2;     // 84 MiB
  const size_t need  = o_lg  + (size_t)BS * NLG * 4;       // ~308 MiB total

  bool have_wl = ws_size >= 1024 * 1024;
  unsigned* cnt = (unsigned*)((char*)d_ws + o_cnt);
  unsigned* wl  = (unsigned*)((char*)d_ws + o_wl);
  unsigned cap  = 0;
  if (have_wl) {
    size_t avail = (ws_size >= need) ? (size_t)WL_CAP
                                     : (ws_size - o_wl) / 4;
    cap = (unsigned)(avail < WL_CAP ? avail : WL_CAP);
  }

  if (ws_size >= need) {
    half_t* xh  = (half_t*)((char*)d_ws + o_xh);
    half_t* xl  = (half_t*)((char*)d_ws + o_xl);
    half_t* wsm = (half_t*)((char*)d_ws + o_wsm);
    half_t* wh  = (half_t*)((char*)d_ws + o_wh);
    half_t* wlo = (half_t*)((char*)d_ws + o_wlo);
    float*  wlt = (float*)((char*)d_ws + o_wlt);
    half_t* P   = (half_t*)((char*)d_ws + o_p);
    float*  Lg  = (float*)((char*)d_ws + o_lg);

    k_prep<<<3072, 256, 0, stream>>>(x, xh, xl, nW, wsm, cnt);
    k_transw<<<dim3(NPAR / 384, DIN / 32), 256, 0, stream>>>(pW, wsm, wh, wlo, wlt);
    k_gemm_logit<<<NT_LG * MT, 256, 0, stream>>>(xh, xl, wh, wlo, Lg, pb);
    k_gemm_sm<<<NT_SM * MT, 256, 0, stream>>>(xh, wsm, P, pb, nb);
    k_pointwise<<<dim3(BS, DOUT / 256), 256, 0, stream>>>(P, Lg, t, out, cnt,
                                                          have_wl ? wl : nullptr, cap);
    if (have_wl)
      k_redo<<<256, 256, 0, stream>>>(x, t, pW, pb, nW, nb, P, wlt, 1, cnt, wl, cap, out);
  } else {
    if (have_wl) k_zero<<<1, 64, 0, stream>>>(cnt);
    k_naive<<<dim3(BS, DOUT / 256), 256, 0, stream>>>(x, t, pW, pb, nW, nb, out, cnt,
                                                      have_wl ? wl : nullptr, cap);
    if (have_wl)
      k_redo<<<256, 256, 0, stream>>>(x, t, pW, pb, nW, nb, nullptr, nullptr, 0,
                                      cnt, wl, cap, out);
  }
}

// Round 7
// 575.571 us; speedup vs baseline: 2.8990x; 1.0740x over previous
//
#include <hip/hip_runtime.h>
#include <cstdint>
#include <cstddef>

// Problem constants (fixed by the reference setup)
#define BS    2048
#define DIN   1024
#define DOUT  1024
#define SSEG  10
#define NPAR  30720          // dout * S * 3
#define NPK   20480          // packed smooth cols: S*DOUT*2 (ch1,ch2)
#define NCOL2 21504          // NPK + DOUT (norm appended)
#define NLG   10240          // S * DOUT logit columns (channel 0)
#define NT_LG 80             // logit n-tiles
#define NT_SM 168            // smooth n-tiles
#define MT    16             // m-tiles (BS/128)
#define TAU   5e-5f          // near-boundary radius (~10x worst fp32-pipeline kp error)
#define WL_CAP 1048576u      // worklist capacity (entries)

// prep kernel regions
#define NB_SPLIT 2048        // x fp16x2 split blocks
#define NB_NORM  1024        // norm_W transpose blocks
#define NB_TRW   2560        // param_W transpose blocks (80 x 32)

typedef _Float16 half_t;
typedef __attribute__((ext_vector_type(8))) _Float16 half8;
typedef __attribute__((ext_vector_type(4))) _Float16 half4;
typedef __attribute__((ext_vector_type(2))) _Float16 half2v;
typedef __attribute__((ext_vector_type(4))) float   floatx4;

__device__ __forceinline__ void gload16(const void* g, void* l) {
  __builtin_amdgcn_global_load_lds(
      (const __attribute__((address_space(1))) void*)g,
      (__attribute__((address_space(3))) void*)l, 16, 0, 0);
}

// ---------------------------------------------------------------------------
__global__ void k_zero(unsigned* c) { if (threadIdx.x == 0) *c = 0; }

// ---------------------------------------------------------------------------
// Prep (3 regions):
//  [0, 2048):        x -> xh/xl fp16x2 split (+ zero worklist counter)
//  [2048, 3072):     norm_W transpose -> wsm rows [NPK, NCOL2)
//  [3072, 5632):     param_W 32k x 384col tiles ->
//                      wsm (ch1/ch2 fp16), wh/wlo (fp16x2 of 32w), wlt (fp32)
//                    emit phase uses 16B vectorized stores: 4 (or 8) lanes
//                    cover one full 64B line -> no partial-line RMW.
// ---------------------------------------------------------------------------
__global__ __launch_bounds__(256) void k_prep(const float* __restrict__ x,
                                              half_t* __restrict__ xh,
                                              half_t* __restrict__ xl,
                                              const float* __restrict__ nW,
                                              const float* __restrict__ pW,
                                              half_t* __restrict__ wsm,
                                              half_t* __restrict__ wh,
                                              half_t* __restrict__ wlo,
                                              float* __restrict__ wlt,
                                              unsigned* __restrict__ cnt) {
  __shared__ float tile[32][384];              // 48 KB (transw region)
  int bid = blockIdx.x;
  int tid = threadIdx.x;

  if (bid < NB_SPLIT) {
    if (bid == 0 && tid == 0) *cnt = 0;
    int i = bid * 256 + tid;                   // float4 groups over BS*DIN
    floatx4 v = ((const floatx4*)x)[i];
    half4 h, l;
    #pragma unroll
    for (int c = 0; c < 4; c++) { h[c] = (half_t)v[c]; l[c] = (half_t)(v[c] - (float)h[c]); }
    ((half4*)xh)[i] = h;
    ((half4*)xl)[i] = l;
    return;
  }

  if (bid < NB_SPLIT + NB_NORM) {
    int b2 = bid - NB_SPLIT;                   // 0..1023
    int col0 = (b2 & 31) * 32;
    int k0   = (b2 >> 5) * 32;
    int tx = tid & 31;
    int ty = tid >> 5;
    float* t33 = &tile[0][0];                  // reuse LDS as 32x33
    #pragma unroll
    for (int r = ty; r < 32; r += 8)
      t33[r * 33 + tx] = nW[(size_t)(k0 + r) * DOUT + col0 + tx];
    __syncthreads();
    #pragma unroll
    for (int r = ty; r < 32; r += 8)
      wsm[(size_t)(col0 + r + NPK) * DIN + k0 + tx] = (half_t)t33[tx * 33 + r];
    return;
  }

  // ---- transw region ----
  int b3 = bid - NB_SPLIT - NB_NORM;           // 0..2559
  int bx = b3 % 80;                            // 384-col group
  int k0 = (b3 / 80) * 32;                     // k tile
  int s  = bx >> 3;                            // logit segment
  int d0 = (bx & 7) * 128;

  const float* sb = pW + (size_t)k0 * NPAR + bx * 384;
  for (int i = tid; i < 32 * 96; i += 256) {   // 12 coalesced float4/thread
    int r = i / 96, q = i - r * 96;
    ((floatx4*)&tile[r][0])[q] = ((const floatx4*)(sb + (size_t)r * NPAR))[q];
  }
  __syncthreads();

  // emit: 3072 16B chunks, 12 per thread. LDS col reads are broadcast within
  // lane groups and hit distinct banks across groups (3j mod 32 permutes).
  for (int ci = tid; ci < 3072; ci += 256) {
    if (ci < 1024) {                           // wsm ch1/ch2: 256 rows x 4 chunks
      int rl = ci >> 2, kc = ci & 3;
      int jj = rl >> 1, cbit = rl & 1;
      int col = 3 * jj + 1 + cbit;
      half8 v;
      #pragma unroll
      for (int m = 0; m < 8; m++) v[m] = (half_t)tile[kc * 8 + m][col];
      *(half8*)(wsm + (size_t)(s * 2048 + 2 * (d0 + jj) + cbit) * DIN + k0 + kc * 8) = v;
    } else if (ci < 1536) {                    // wh: 128 rows x 4 chunks
      int u = ci - 1024;
      int jj = u >> 2, kc = u & 3;
      half8 v;
      #pragma unroll
      for (int m = 0; m < 8; m++) v[m] = (half_t)(tile[kc * 8 + m][3 * jj] * 32.0f);
      *(half8*)(wh + (size_t)(s * 1024 + d0 + jj) * DIN + k0 + kc * 8) = v;
    } else if (ci < 2048) {                    // wlo: 128 rows x 4 chunks
      int u = ci - 1536;
      int jj = u >> 2, kc = u & 3;
      half8 v;
      #pragma unroll
      for (int m = 0; m < 8; m++) {
        float raw = tile[kc * 8 + m][3 * jj] * 32.0f;   // exact pow2 scale
        half_t h = (half_t)raw;
        v[m] = (half_t)(raw - (float)h);
      }
      *(half8*)(wlo + (size_t)(s * 1024 + d0 + jj) * DIN + k0 + kc * 8) = v;
    } else {                                   // wlt fp32: 128 rows x 8 chunks
      int u = ci - 2048;
      int jj = u >> 3, kc = u & 7;
      floatx4 v;
      #pragma unroll
      for (int m = 0; m < 4; m++) v[m] = tile[kc * 4 + m][3 * jj];
      *(floatx4*)(wlt + (size_t)(s * 1024 + d0 + jj) * DIN + k0 + kc * 4) = v;
    }
  }
}

// ---------------------------------------------------------------------------
// Logit GEMM, fp16x2: Lg(BS x NLG fp32) = (xh+xl)(wh+wlo)^T/32 + bias
// (drops xl*wlo term). Plain 2D grid (nt, mt) — measured best (r3: 159.7 us).
// ---------------------------------------------------------------------------
__global__ __launch_bounds__(256) void k_gemm_logit(const half_t* __restrict__ Ah,
                                                    const half_t* __restrict__ Al,
                                                    const half_t* __restrict__ Bh,
                                                    const half_t* __restrict__ Bl,
                                                    float* __restrict__ Lg,
                                                    const float* __restrict__ pb) {
  __shared__ __attribute__((aligned(16))) half_t sAh[128 * 32];
  __shared__ __attribute__((aligned(16))) half_t sAl[128 * 32];
  __shared__ __attribute__((aligned(16))) half_t sBh[128 * 32];
  __shared__ __attribute__((aligned(16))) half_t sBl[128 * 32];
  const int K = DIN;
  int m0 = blockIdx.y * 128, n0 = blockIdx.x * 128;
  int tid = threadIdx.x, w = tid >> 6, L = tid & 63;
  int wm = (w >> 1) * 64, wn = (w & 1) * 64;
  int l15 = L & 15, quad = L >> 4;

  size_t arow = (size_t)(m0 + w * 16 + (L >> 2)) * K + (L & 3) * 8;
  size_t brow = (size_t)(n0 + w * 16 + (L >> 2)) * K + (L & 3) * 8;
  char* lah = (char*)sAh + w * 1024;
  char* lal = (char*)sAl + w * 1024;
  char* lbh = (char*)sBh + w * 1024;
  char* lbl = (char*)sBl + w * 1024;

  floatx4 acc[4][4] = {};

  for (int k0 = 0; k0 < K; k0 += 32) {
    __syncthreads();
    gload16(Ah + arow + k0,          lah);
    gload16(Ah + arow + 64 * K + k0, lah + 4096);
    gload16(Al + arow + k0,          lal);
    gload16(Al + arow + 64 * K + k0, lal + 4096);
    gload16(Bh + brow + k0,          lbh);
    gload16(Bh + brow + 64 * K + k0, lbh + 4096);
    gload16(Bl + brow + k0,          lbl);
    gload16(Bl + brow + 64 * K + k0, lbl + 4096);
    __syncthreads();

    #pragma unroll
    for (int mi = 0; mi < 4; mi++) {
      half8 afh = *(const half8*)((const char*)sAh + (wm + mi * 16 + l15) * 64 + quad * 16);
      half8 afl = *(const half8*)((const char*)sAl + (wm + mi * 16 + l15) * 64 + quad * 16);
      #pragma unroll
      for (int ni = 0; ni < 4; ni++) {
        half8 bfh = *(const half8*)((const char*)sBh + (wn + ni * 16 + l15) * 64 + quad * 16);
        half8 bfl = *(const half8*)((const char*)sBl + (wn + ni * 16 + l15) * 64 + quad * 16);
        floatx4 a = acc[mi][ni];
        a = __builtin_amdgcn_mfma_f32_16x16x32_f16(afh, bfh, a, 0, 0, 0);
        a = __builtin_amdgcn_mfma_f32_16x16x32_f16(afl, bfh, a, 0, 0, 0);
        a = __builtin_amdgcn_mfma_f32_16x16x32_f16(afh, bfl, a, 0, 0, 0);
        acc[mi][ni] = a;
      }
    }
  }

  #pragma unroll
  for (int ni = 0; ni < 4; ni++) {
    int col = n0 + wn + ni * 16 + l15;                       // packed s*1024+d
    float bias = pb[(col >> 10) * 3072 + (col & 1023) * 3];
    #pragma unroll
    for (int mi = 0; mi < 4; mi++) {
      int row = m0 + wm + mi * 16 + quad * 4;
      floatx4 v = acc[mi][ni];
      #pragma unroll
      for (int r = 0; r < 4; r++)
        Lg[(size_t)(row + r) * NLG + col] = v[r] * 0.03125f + bias;
    }
  }
}

// ---------------------------------------------------------------------------
// Smooth GEMM: P(BS x NCOL2, fp16) = xh * wsm^T + bias. Plain 2D grid.
// ---------------------------------------------------------------------------
__global__ __launch_bounds__(256) void k_gemm_sm(const half_t* __restrict__ A,
                                                 const half_t* __restrict__ B,
                                                 half_t* __restrict__ P,
                                                 const float* __restrict__ pb,
                                                 const float* __restrict__ nb) {
  __shared__ __attribute__((aligned(16))) half_t As[128 * 32];
  __shared__ __attribute__((aligned(16))) half_t Bs[128 * 32];
  const int K = DIN;
  int m0 = blockIdx.y * 128, n0 = blockIdx.x * 128;
  int tid = threadIdx.x, w = tid >> 6, L = tid & 63;
  int wm = (w >> 1) * 64, wn = (w & 1) * 64;
  int l15 = L & 15, quad = L >> 4;

  const half_t* ga = A + (size_t)(m0 + w * 16 + (L >> 2)) * K + (L & 3) * 8;
  const half_t* gb = B + (size_t)(n0 + w * 16 + (L >> 2)) * K + (L & 3) * 8;
  char* lA = (char*)As + w * 1024;
  char* lB = (char*)Bs + w * 1024;

  floatx4 acc[4][4] = {};

  for (int k0 = 0; k0 < K; k0 += 32) {
    __syncthreads();
    gload16(ga + k0,          lA);
    gload16(ga + 64 * K + k0, lA + 4096);
    gload16(gb + k0,          lB);
    gload16(gb + 64 * K + k0, lB + 4096);
    __syncthreads();

    half8 af[4], bf[4];
    #pragma unroll
    for (int mi = 0; mi < 4; mi++)
      af[mi] = *(const half8*)((const char*)As + (wm + mi * 16 + l15) * 64 + quad * 16);
    #pragma unroll
    for (int ni = 0; ni < 4; ni++)
      bf[ni] = *(const half8*)((const char*)Bs + (wn + ni * 16 + l15) * 64 + quad * 16);
    #pragma unroll
    for (int mi = 0; mi < 4; mi++)
      #pragma unroll
      for (int ni = 0; ni < 4; ni++)
        acc[mi][ni] = __builtin_amdgcn_mfma_f32_16x16x32_f16(af[mi], bf[ni], acc[mi][ni], 0, 0, 0);
  }

  #pragma unroll
  for (int ni = 0; ni < 4; ni++) {
    int col = n0 + wn + ni * 16 + l15;
    float bias;
    if (col < NPK) {
      int s = col >> 11, rem = col & 2047;
      bias = pb[s * 3072 + 3 * (rem >> 1) + 1 + (rem & 1)];
    } else {
      bias = nb[col - NPK];
    }
    #pragma unroll
    for (int mi = 0; mi < 4; mi++) {
      int row = m0 + wm + mi * 16 + quad * 4;
      floatx4 v = acc[mi][ni];
      #pragma unroll
      for (int r = 0; r < 4; r++)
        P[(size_t)(row + r) * NCOL2 + col] = (half_t)(v[r] + bias);
    }
  }
}

// ---------------------------------------------------------------------------
// fp32 formula; mind = min_j |t - kp[j]| for near-boundary flagging
// ---------------------------------------------------------------------------
__device__ __forceinline__ float spiking_eval(const float* p, float tt, float* mind) {
  float mx = -1e30f;
  #pragma unroll
  for (int s = 0; s < SSEG; s++) mx = fmaxf(mx, p[3 * s]);
  float ew[10], wsum = 0.0f;
  #pragma unroll
  for (int s = 0; s < SSEG; s++) { ew[s] = __expf(p[3 * s] - mx); wsum += ew[s]; }
  float inv = 1.0f / wsum;

  float kp[11];
  kp[0] = -1.0f;
  float cum = 0.0f, md = 1e30f;
  #pragma unroll
  for (int s = 0; s < SSEG; s++) {
    cum += ew[s] * inv;
    kp[s + 1] = cum * 2.0f - 1.0f;
    md = fminf(md, fabsf(tt - kp[s + 1]));
  }
  *mind = md;

  float vf[10], resid[10];
  float lm = 0.0f, rm = 0.0f, integ = 0.0f;
  #pragma unroll
  for (int s = 0; s < SSEG; s++) {
    float p1 = p[3 * s + 1], p2 = p[3 * s + 2];
    float e2 = __expf(2.0f * fabsf(p1));
    float th = copysignf(1.0f - 2.0f / (e2 + 1.0f), p1);
    resid[s] = th * tt + p2;
    float st = kp[s], en = kp[s + 1];
    bool v = ((tt >= st) && (tt < en)) || ((tt == 1.0f) && (en == 1.0f));
    float vv = v ? 1.0f : 0.0f;
    vf[s] = vv;
    lm += (tt - st) * vv;
    rm += (en - tt) * vv;
    integ += 0.5f * th * (en * en - st * st) + p2 * (ew[s] * inv);
  }
  float resLV = 0.0f, resV = 0.0f, resRV = 0.0f;
  #pragma unroll
  for (int s = 0; s < SSEG; s++) {
    float lv = (s == 0) ? vf[0] : vf[s - 1];
    float rv = (s == 9) ? vf[9] : vf[s + 1];
    resLV += resid[s] * lv;
    resV  += resid[s] * vf[s];
    resRV += resid[s] * rv;
  }
  float lw = 1.0f / (1.0f + __expf(50.0f * lm));
  float rw = 1.0f / (1.0f + __expf(50.0f * rm));
  float swt = 1.0f - lw - rw;
  return lw * resLV + swt * resV + rw * resRV - 0.5f * integ + p[30];
}

// ---------------------------------------------------------------------------
// Pointwise: logits fp32 from Lg, ch1/2+norm fp16 from P. Flags near-boundary.
// ---------------------------------------------------------------------------
__global__ __launch_bounds__(256) void k_pointwise(const half_t* __restrict__ P,
                                                   const float* __restrict__ Lg,
                                                   const float* __restrict__ t,
                                                   float* __restrict__ out,
                                                   unsigned* __restrict__ cnt,
                                                   unsigned* __restrict__ wl,
                                                   unsigned cap) {
  __shared__ __attribute__((aligned(16))) half_t sp[SSEG * 512];
  int b = blockIdx.x, dg = blockIdx.y, tid = threadIdx.x;
  const half_t* Pb = P + (size_t)b * NCOL2;
  for (int i = tid; i < SSEG * 64; i += 256) {     // 640 x 16B
    int s = i >> 6, e = i & 63;
    ((uint4*)sp)[(s << 6) + e] = ((const uint4*)(Pb + s * 2048 + dg * 512))[e];
  }
  float tt = t[b];
  float nt = (float)Pb[NPK + dg * 256 + tid];
  const float* Lb = Lg + (size_t)b * NLG + dg * 256 + tid;
  __syncthreads();

  float p[31];
  #pragma unroll
  for (int s = 0; s < SSEG; s++) {
    p[3 * s] = Lb[s * 1024];                       // accurate logit (bias incl.)
    half2v hv = ((const half2v*)sp)[s * 256 + tid];  // 4B/lane, conflict-free
    p[3 * s + 1] = (float)hv.x;
    p[3 * s + 2] = (float)hv.y;
  }
  p[30] = nt;
  float mind;
  float r = spiking_eval(p, tt, &mind);
  int d = dg * 256 + tid;
  out[(size_t)b * DOUT + d] = r;
  if (wl != nullptr && mind < TAU) {
    unsigned idx = atomicAdd(cnt, 1u);
    if (idx < cap) wl[idx] = ((unsigned)b << 10) | (unsigned)d;
  }
}

// ---------------------------------------------------------------------------
// Fallback: fused naive fp32 + flagging (tiny-workspace insurance)
// ---------------------------------------------------------------------------
__global__ __launch_bounds__(256) void k_naive(const float* __restrict__ x,
                                               const float* __restrict__ t,
                                               const float* __restrict__ pW,
                                               const float* __restrict__ pb,
                                               const float* __restrict__ nW,
                                               const float* __restrict__ nb,
                                               float* __restrict__ out,
                                               unsigned* __restrict__ cnt,
                                               unsigned* __restrict__ wl,
                                               unsigned cap) {
  __shared__ float xs[DIN];
  int b = blockIdx.x, dg = blockIdx.y, tid = threadIdx.x;
  for (int i = tid; i < DIN; i += 256) xs[i] = x[(size_t)b * DIN + i];
  __syncthreads();
  int d = dg * 256 + tid;
  float acc[31];
  #pragma unroll
  for (int i = 0; i < 31; i++) acc[i] = 0.0f;
  for (int k = 0; k < DIN; k++) {
    float xv = xs[k];
    const float* wr = pW + (size_t)k * NPAR + 3 * d;
    #pragma unroll
    for (int s = 0; s < SSEG; s++) {
      acc[3 * s]     += xv * wr[s * 3072];
      acc[3 * s + 1] += xv * wr[s * 3072 + 1];
      acc[3 * s + 2] += xv * wr[s * 3072 + 2];
    }
    acc[30] += xv * nW[(size_t)k * DOUT + d];
  }
  #pragma unroll
  for (int s = 0; s < SSEG; s++) {
    acc[3 * s]     += pb[s * 3072 + 3 * d];
    acc[3 * s + 1] += pb[s * 3072 + 3 * d + 1];
    acc[3 * s + 2] += pb[s * 3072 + 3 * d + 2];
  }
  acc[30] += nb[d];
  float mind;
  float r = spiking_eval(acc, t[b], &mind);
  out[(size_t)b * DOUT + d] = r;
  if (wl != nullptr && mind < TAU) {
    unsigned idx = atomicAdd(cnt, 1u);
    if (idx < cap) wl[idx] = ((unsigned)b << 10) | (unsigned)d;
  }
}

// ---------------------------------------------------------------------------
// f64 redo: one wave per flagged (b,d). haveP: coalesced WLt logit weights +
// fp16 smooth channels from P. !haveP: pW gather (fallback path).
// ---------------------------------------------------------------------------
__global__ __launch_bounds__(256) void k_redo(const float* __restrict__ x,
                                              const float* __restrict__ t,
                                              const float* __restrict__ pW,
                                              const float* __restrict__ pb,
                                              const float* __restrict__ nW,
                                              const float* __restrict__ nb,
                                              const half_t* __restrict__ P,
                                              const float* __restrict__ WLt,
                                              int haveP,
                                              const unsigned* __restrict__ cnt,
                                              const unsigned* __restrict__ wl,
                                              unsigned cap,
                                              float* __restrict__ out) {
  unsigned n = *cnt;
  if (n > cap) n = cap;
  int lane = threadIdx.x & 63;
  unsigned wave = (blockIdx.x * 256 + threadIdx.x) >> 6;
  unsigned nwaves = (gridDim.x * 256) >> 6;

  for (unsigned e = wave; e < n; e += nwaves) {
    unsigned code = wl[e];
    int b = (int)(code >> 10), d = (int)(code & 1023);

    double lg[10], sl[10], ic[10], nt = 0.0;
    #pragma unroll
    for (int s = 0; s < SSEG; s++) { lg[s] = 0.0; sl[s] = 0.0; ic[s] = 0.0; }

    if (haveP) {
      for (int k = lane; k < DIN; k += 64) {     // coalesced WLt rows
        double xv = (double)x[(size_t)b * DIN + k];
        #pragma unroll
        for (int s = 0; s < SSEG; s++)
          lg[s] += xv * (double)WLt[(size_t)(s * 1024 + d) * DIN + k];
      }
    } else {
      for (int k = lane; k < DIN; k += 64) {
        double xv = (double)x[(size_t)b * DIN + k];
        const float* wr = pW + (size_t)k * NPAR + 3 * d;
        #pragma unroll
        for (int s = 0; s < SSEG; s++) {
          lg[s] += xv * (double)wr[s * 3072];
          sl[s] += xv * (double)wr[s * 3072 + 1];
          ic[s] += xv * (double)wr[s * 3072 + 2];
        }
        nt += xv * (double)nW[(size_t)k * DOUT + d];
      }
    }
    #pragma unroll
    for (int off = 32; off > 0; off >>= 1) {
      #pragma unroll
      for (int s = 0; s < SSEG; s++) lg[s] += __shfl_down(lg[s], off);
      if (!haveP) {
        #pragma unroll
        for (int s = 0; s < SSEG; s++) {
          sl[s] += __shfl_down(sl[s], off);
          ic[s] += __shfl_down(ic[s], off);
        }
        nt += __shfl_down(nt, off);
      }
    }

    if (lane == 0) {
      double slope[10], icpt[10], ntv;
      if (haveP) {
        const half_t* Pr = P + (size_t)b * NCOL2;
        #pragma unroll
        for (int s = 0; s < SSEG; s++) {
          slope[s] = tanh((double)(float)Pr[s * 2048 + 2 * d]);
          icpt[s]  = (double)(float)Pr[s * 2048 + 2 * d + 1];
        }
        ntv = (double)(float)Pr[NPK + d];
      } else {
        #pragma unroll
        for (int s = 0; s < SSEG; s++) {
          slope[s] = tanh(sl[s] + (double)pb[s * 3072 + 3 * d + 1]);
          icpt[s]  = ic[s] + (double)pb[s * 3072 + 3 * d + 2];
        }
        ntv = nt + (double)nb[d];
      }
      #pragma unroll
      for (int s = 0; s < SSEG; s++) lg[s] += (double)pb[s * 3072 + 3 * d];

      double mx = -1e300;
      #pragma unroll
      for (int s = 0; s < SSEG; s++) mx = fmax(mx, lg[s]);
      double ew[10], ws = 0.0;
      #pragma unroll
      for (int s = 0; s < SSEG; s++) { ew[s] = exp(lg[s] - mx); ws += ew[s]; }

      double kp[11];
      kp[0] = -1.0;
      double cum = 0.0;
      #pragma unroll
      for (int s = 0; s < SSEG; s++) { cum += ew[s] / ws; kp[s + 1] = cum * 2.0 - 1.0; }

      double tt = (double)t[b];
      double vf[10], resid[10], lm = 0.0, rm = 0.0, integ = 0.0;
      #pragma unroll
      for (int s = 0; s < SSEG; s++) {
        double st = kp[s], en = kp[s + 1];
        bool v = ((tt >= st) && (tt < en)) || ((tt == 1.0) && (en == 1.0));
        double vv = v ? 1.0 : 0.0;
        vf[s] = vv;
        resid[s] = slope[s] * tt + icpt[s];
        lm += (tt - st) * vv;
        rm += (en - tt) * vv;
        integ += 0.5 * slope[s] * (en * en - st * st) + icpt[s] * (ew[s] / ws);
      }
      double rLV = 0.0, rV = 0.0, rRV = 0.0;
      #pragma unroll
      for (int s = 0; s < SSEG; s++) {
        double lv = (s == 0) ? vf[0] : vf[s - 1];
        double rv = (s == 9) ? vf[9] : vf[s + 1];
        rLV += resid[s] * lv;
        rV  += resid[s] * vf[s];
        rRV += resid[s] * rv;
      }
      double lw = 1.0 / (1.0 + exp(50.0 * lm));
      double rw = 1.0 / (1.0 + exp(50.0 * rm));
      double res = lw * rLV + (1.0 - lw - rw) * rV + rw * rRV - 0.5 * integ + ntv;
      out[(size_t)b * DOUT + d] = (float)res;
    }
  }
}

// ---------------------------------------------------------------------------
extern "C" void kernel_launch(void* const* d_in, const int* in_sizes, int n_in,
                              void* d_out, int out_size, void* d_ws, size_t ws_size,
                              hipStream_t stream) {
  const float* x  = (const float*)d_in[0];
  const float* t  = (const float*)d_in[1];
  const float* pW = (const float*)d_in[2];
  const float* pb = (const float*)d_in[3];
  const float* nW = (const float*)d_in[4];
  const float* nb = (const float*)d_in[5];
  float* out = (float*)d_out;

  // workspace layout (counter+worklist first so the fallback works with tiny ws)
  const size_t o_cnt = 0;
  const size_t o_wl  = 64;
  const size_t o_xh  = o_wl  + (size_t)WL_CAP * 4;         //  4 MiB
  const size_t o_xl  = o_xh  + (size_t)BS * DIN * 2;       //  4 MiB
  const size_t o_wsm = o_xl  + (size_t)BS * DIN * 2;       // 44 MiB (NCOL2 fp16)
  const size_t o_wh  = o_wsm + (size_t)NCOL2 * DIN * 2;    // 20 MiB
  const size_t o_wlo = o_wh  + (size_t)NLG * DIN * 2;      // 20 MiB
  const size_t o_wlt = o_wlo + (size_t)NLG * DIN * 2;      // 40 MiB (fp32 logit W^T)
  const size_t o_p   = o_wlt + (size_t)NLG * DIN * 4;      // 88 MiB (fp16 P2)
  const size_t o_lg  = o_p   + (size_t)BS * NCOL2 * 2;     // 84 MiB
  const size_t need  = o_lg  + (size_t)BS * NLG * 4;       // ~308 MiB total

  bool have_wl = ws_size >= 1024 * 1024;
  unsigned* cnt = (unsigned*)((char*)d_ws + o_cnt);
  unsigned* wl  = (unsigned*)((char*)d_ws + o_wl);
  unsigned cap  = 0;
  if (have_wl) {
    size_t avail = (ws_size >= need) ? (size_t)WL_CAP
                                     : (ws_size - o_wl) / 4;
    cap = (unsigned)(avail < WL_CAP ? avail : WL_CAP);
  }

  if (ws_size >= need) {
    half_t* xh  = (half_t*)((char*)d_ws + o_xh);
    half_t* xl  = (half_t*)((char*)d_ws + o_xl);
    half_t* wsm = (half_t*)((char*)d_ws + o_wsm);
    half_t* wh  = (half_t*)((char*)d_ws + o_wh);
    half_t* wlo = (half_t*)((char*)d_ws + o_wlo);
    float*  wlt = (float*)((char*)d_ws + o_wlt);
    half_t* P   = (half_t*)((char*)d_ws + o_p);
    float*  Lg  = (float*)((char*)d_ws + o_lg);

    k_prep<<<NB_SPLIT + NB_NORM + NB_TRW, 256, 0, stream>>>(x, xh, xl, nW, pW,
                                                            wsm, wh, wlo, wlt, cnt);
    k_gemm_logit<<<dim3(NT_LG, MT), 256, 0, stream>>>(xh, xl, wh, wlo, Lg, pb);
    k_gemm_sm<<<dim3(NT_SM, MT), 256, 0, stream>>>(xh, wsm, P, pb, nb);
    k_pointwise<<<dim3(BS, DOUT / 256), 256, 0, stream>>>(P, Lg, t, out, cnt,
                                                          have_wl ? wl : nullptr, cap);
    if (have_wl)
      k_redo<<<256, 256, 0, stream>>>(x, t, pW, pb, nW, nb, P, wlt, 1, cnt, wl, cap, out);
  } else {
    if (have_wl) k_zero<<<1, 64, 0, stream>>>(cnt);
    k_naive<<<dim3(BS, DOUT / 256), 256, 0, stream>>>(x, t, pW, pb, nW, nb, out, cnt,
                                                      have_wl ? wl : nullptr, cap);
    if (have_wl)
      k_redo<<<256, 256, 0, stream>>>(x, t, pW, pb, nW, nb, nullptr, nullptr, 0,
                                      cnt, wl, cap, out);
  }
}